// Round 1
// baseline (11066.415 us; speedup 1.0000x reference)
//
#include <hip/hip_runtime.h>
#include <math.h>

// Problem constants (B=64, L=321, D=512, DFF=2048, H=8, E=64, P=16, TOPK=10)
#define N_ROWS 20544   // B*L
#define LSEQ   321
#define BB     64
#define HH     8
#define EE     64
#define DD     512
#define DFF    2048

// ---------------------------------------------------------------------------
// Generic tiled SGEMM: C[M,N] = POST( PRE(A)[M,K] @ W[K,N] + bias[N] (+ R) )
// PRE: 0 none, 2 leaky(0.5)  |  POST: 0 none, 1 relu  |  RES: 0/1
// Requires M%64==0, N%64==0, K%16==0 (true for every call here).
// ---------------------------------------------------------------------------
template<int PRE, int POST, int RES>
__global__ __launch_bounds__(256)
void sgemm_kernel(const float* __restrict__ A, const float* __restrict__ W,
                  const float* __restrict__ bias, const float* __restrict__ R,
                  float* __restrict__ C, int M, int K, int N)
{
    __shared__ float As[16][68];   // [k][row], pad 68 -> 2-way max (free)
    __shared__ float Bs[16][64];   // [k][col]
    const int t  = threadIdx.x;
    const int tx = t & 15, ty = t >> 4;
    const int row0 = blockIdx.x << 6, col0 = blockIdx.y << 6;
    const int ar = t >> 2;          // 0..63 row within tile
    const int ak = (t & 3) << 2;    // 0,4,8,12 k within tile
    const float* Ap = A + (size_t)(row0 + ar) * K + ak;
    const float* Wp = W + (size_t)ty * N + col0 + (tx << 2);
    float acc[4][4] = {};
    for (int k0 = 0; k0 < K; k0 += 16) {
        float4 av = *(const float4*)(Ap + k0);
        if (PRE == 2) {
            av.x = av.x >= 0.f ? av.x : 0.5f * av.x;
            av.y = av.y >= 0.f ? av.y : 0.5f * av.y;
            av.z = av.z >= 0.f ? av.z : 0.5f * av.z;
            av.w = av.w >= 0.f ? av.w : 0.5f * av.w;
        }
        float4 wv = *(const float4*)(Wp + (size_t)k0 * N);
        As[ak + 0][ar] = av.x;
        As[ak + 1][ar] = av.y;
        As[ak + 2][ar] = av.z;
        As[ak + 3][ar] = av.w;
        *(float4*)&Bs[ty][tx << 2] = wv;
        __syncthreads();
        #pragma unroll
        for (int kk = 0; kk < 16; ++kk) {
            const float4 a4 = *(const float4*)&As[kk][ty << 2];
            const float4 b4 = *(const float4*)&Bs[kk][tx << 2];
            const float a[4] = {a4.x, a4.y, a4.z, a4.w};
            const float b[4] = {b4.x, b4.y, b4.z, b4.w};
            #pragma unroll
            for (int i = 0; i < 4; ++i)
                #pragma unroll
                for (int j = 0; j < 4; ++j)
                    acc[i][j] = fmaf(a[i], b[j], acc[i][j]);
        }
        __syncthreads();
    }
    const float4 bi = *(const float4*)(bias + col0 + (tx << 2));
    #pragma unroll
    for (int i = 0; i < 4; ++i) {
        const int row = row0 + (ty << 2) + i;
        float4 c;
        c.x = acc[i][0] + bi.x;
        c.y = acc[i][1] + bi.y;
        c.z = acc[i][2] + bi.z;
        c.w = acc[i][3] + bi.w;
        if (RES) {
            const float4 r4 = *(const float4*)(R + (size_t)row * N + col0 + (tx << 2));
            c.x += r4.x; c.y += r4.y; c.z += r4.z; c.w += r4.w;
        }
        if (POST == 1) {
            c.x = fmaxf(c.x, 0.f); c.y = fmaxf(c.y, 0.f);
            c.z = fmaxf(c.z, 0.f); c.w = fmaxf(c.w, 0.f);
        }
        *(float4*)(C + (size_t)row * N + col0 + (tx << 2)) = c;
    }
}

// ---------------------------------------------------------------------------
// scores[b,h,l,s] = sum_e q[b,l,h,e] * k[b,s,h,e]   (q,k stored as [B*L, 512])
// grid: (ceil(L/32), ceil(L/32), B*H), block 256
// ---------------------------------------------------------------------------
__global__ __launch_bounds__(256)
void scores_kernel(const float* __restrict__ Q, const float* __restrict__ Kx,
                   float* __restrict__ Sc)
{
    const int bh = blockIdx.z, b = bh >> 3, h = bh & 7;
    const int l0 = blockIdx.x << 5, s0 = blockIdx.y << 5;
    __shared__ float qs[32][68];
    __shared__ float ks[32][68];
    const int t = threadIdx.x;
    #pragma unroll
    for (int pass = 0; pass < 2; ++pass) {
        const int r = (t >> 4) + (pass << 4);
        const int c = (t & 15) << 2;
        const int l = l0 + r, s = s0 + r;
        float4 qv = make_float4(0.f, 0.f, 0.f, 0.f);
        float4 kv = make_float4(0.f, 0.f, 0.f, 0.f);
        if (l < LSEQ) qv = *(const float4*)(Q + ((size_t)(b * LSEQ + l)) * DD + h * EE + c);
        if (s < LSEQ) kv = *(const float4*)(Kx + ((size_t)(b * LSEQ + s)) * DD + h * EE + c);
        *(float4*)&qs[r][c] = qv;
        *(float4*)&ks[r][c] = kv;
    }
    __syncthreads();
    const int sx = t & 31, ly = t >> 5;   // 32 s-cols, 8 l-groups of 4
    float accv[4] = {0.f, 0.f, 0.f, 0.f};
    for (int e = 0; e < EE; e += 4) {
        const float4 kv = *(const float4*)&ks[sx][e];
        #pragma unroll
        for (int i = 0; i < 4; ++i) {
            const float4 qv = *(const float4*)&qs[(ly << 2) + i][e];
            accv[i] += qv.x * kv.x + qv.y * kv.y + qv.z * kv.z + qv.w * kv.w;
        }
    }
    const int s = s0 + sx;
    if (s < LSEQ) {
        #pragma unroll
        for (int i = 0; i < 4; ++i) {
            const int l = l0 + (ly << 2) + i;
            if (l < LSEQ)
                Sc[((size_t)bh * LSEQ + l) * LSEQ + s] = accv[i];
        }
    }
}

// ---------------------------------------------------------------------------
// In-place per-row: find 10th largest, mask < kth, softmax(0.125*s).
// One wave per row (row length 321). grid*4 waves == B*H*L exactly.
// ---------------------------------------------------------------------------
__global__ __launch_bounds__(256)
void topk_softmax_kernel(float* __restrict__ S)
{
    const int wave = threadIdx.x >> 6;
    const int lane = threadIdx.x & 63;
    const size_t row = (size_t)blockIdx.x * 4 + wave;
    float* p = S + row * LSEQ;
    float v[6], w[6];
    #pragma unroll
    for (int j = 0; j < 6; ++j) {
        const int idx = lane + (j << 6);
        v[j] = (idx < LSEQ) ? p[idx] : -INFINITY;
        w[j] = v[j];
    }
    float gmax = 0.f, kth = 0.f;
    #pragma unroll
    for (int it = 0; it < 10; ++it) {
        float m = w[0];
        #pragma unroll
        for (int j = 1; j < 6; ++j) m = fmaxf(m, w[j]);
        #pragma unroll
        for (int off = 32; off > 0; off >>= 1)
            m = fmaxf(m, __shfl_xor(m, off, 64));
        if (it == 0) gmax = m;
        kth = m;
        if (it < 9) {
            int which = -1;
            #pragma unroll
            for (int j = 0; j < 6; ++j)
                if (which < 0 && w[j] == m) which = j;
            const unsigned long long msk = __ballot(which >= 0);
            const int first = __ffsll(msk) - 1;
            if (lane == first) {   // remove exactly ONE instance per iteration
                #pragma unroll
                for (int j = 0; j < 6; ++j)
                    if (j == which) w[j] = -INFINITY;
            }
        }
    }
    float ssum = 0.f;
    float e[6];
    #pragma unroll
    for (int j = 0; j < 6; ++j) {
        e[j] = (v[j] >= kth) ? __expf(0.125f * (v[j] - gmax)) : 0.f;
        ssum += e[j];
    }
    #pragma unroll
    for (int off = 32; off > 0; off >>= 1) ssum += __shfl_xor(ssum, off, 64);
    const float inv = 1.f / ssum;
    #pragma unroll
    for (int j = 0; j < 6; ++j) {
        const int idx = lane + (j << 6);
        if (idx < LSEQ) p[idx] = e[j] * inv;
    }
}

// ---------------------------------------------------------------------------
// out[b,l,h,e] = sum_s A[b,h,l,s] * v[b,s,h,e]; out stored [B*L, 512]
// grid: (ceil(L/32), B*H); block 256 computes 32 l x 64 e
// ---------------------------------------------------------------------------
__global__ __launch_bounds__(256)
void av_kernel(const float* __restrict__ A, const float* __restrict__ V,
               float* __restrict__ Out)
{
    const int bh = blockIdx.y, b = bh >> 3, h = bh & 7;
    const int l0 = blockIdx.x << 5;
    __shared__ float As[32][36];
    __shared__ float Vs[32][68];
    const int t = threadIdx.x;
    const int tx = t & 15, ty = t >> 4;
    float acc[2][4] = {};
    for (int s0 = 0; s0 < LSEQ; s0 += 32) {
        {
            const int r = t >> 3, c = (t & 7) << 2;
            const int l = l0 + r;
            const float* ap = A + ((size_t)bh * LSEQ + (l < LSEQ ? l : 0)) * LSEQ + s0 + c;
            #pragma unroll
            for (int jj = 0; jj < 4; ++jj) {
                const int s = s0 + c + jj;
                As[r][c + jj] = (l < LSEQ && s < LSEQ) ? ap[jj] : 0.f;
            }
        }
        #pragma unroll
        for (int pass = 0; pass < 2; ++pass) {
            const int r = (t >> 4) + (pass << 4), c = (t & 15) << 2;
            const int s = s0 + r;
            float4 vv = make_float4(0.f, 0.f, 0.f, 0.f);
            if (s < LSEQ)
                vv = *(const float4*)(V + ((size_t)(b * LSEQ + s)) * DD + h * EE + c);
            *(float4*)&Vs[r][c] = vv;
        }
        __syncthreads();
        #pragma unroll
        for (int ss = 0; ss < 32; ++ss) {
            const float a0 = As[(ty << 1) + 0][ss];
            const float a1 = As[(ty << 1) + 1][ss];
            const float4 vv = *(const float4*)&Vs[ss][tx << 2];
            acc[0][0] = fmaf(a0, vv.x, acc[0][0]);
            acc[0][1] = fmaf(a0, vv.y, acc[0][1]);
            acc[0][2] = fmaf(a0, vv.z, acc[0][2]);
            acc[0][3] = fmaf(a0, vv.w, acc[0][3]);
            acc[1][0] = fmaf(a1, vv.x, acc[1][0]);
            acc[1][1] = fmaf(a1, vv.y, acc[1][1]);
            acc[1][2] = fmaf(a1, vv.z, acc[1][2]);
            acc[1][3] = fmaf(a1, vv.w, acc[1][3]);
        }
        __syncthreads();
    }
    #pragma unroll
    for (int i = 0; i < 2; ++i) {
        const int l = l0 + (ty << 1) + i;
        if (l < LSEQ) {
            float4 o;
            o.x = acc[i][0]; o.y = acc[i][1]; o.z = acc[i][2]; o.w = acc[i][3];
            *(float4*)(Out + ((size_t)(b * LSEQ + l)) * DD + h * EE + (tx << 2)) = o;
        }
    }
}

// ---------------------------------------------------------------------------
// Point-wise attention: per row n, per query l (one thread each):
//   A = softmax_s( dot16(q_l, k_s) * 0.25 ) ; out_l = sum_s A_s * v_s  (16 wide)
// Online softmax, all in registers. q,out: [N, NQ*16]; k,v: [N, NS*16].
// ---------------------------------------------------------------------------
template<int NQ, int NS>
__global__ __launch_bounds__(256)
void pw_attn_kernel(const float* __restrict__ Q, const float* __restrict__ Kx,
                    const float* __restrict__ V, float* __restrict__ Out)
{
    const long long gid = (long long)blockIdx.x * 256 + threadIdx.x;
    const long long n = gid / NQ;
    const int l = (int)(gid % NQ);
    const float* qp = Q + (size_t)n * NQ * 16 + l * 16;
    const float4 q0 = *(const float4*)(qp + 0);
    const float4 q1 = *(const float4*)(qp + 4);
    const float4 q2 = *(const float4*)(qp + 8);
    const float4 q3 = *(const float4*)(qp + 12);
    const float* kp = Kx + (size_t)n * NS * 16;
    const float* vp = V  + (size_t)n * NS * 16;
    float m = -INFINITY, denom = 0.f;
    float acc[16] = {};
    for (int s = 0; s < NS; ++s) {
        const float* kr = kp + s * 16;
        const float4 k0 = *(const float4*)(kr + 0);
        const float4 k1 = *(const float4*)(kr + 4);
        const float4 k2 = *(const float4*)(kr + 8);
        const float4 k3 = *(const float4*)(kr + 12);
        float sc = q0.x*k0.x + q0.y*k0.y + q0.z*k0.z + q0.w*k0.w
                 + q1.x*k1.x + q1.y*k1.y + q1.z*k1.z + q1.w*k1.w
                 + q2.x*k2.x + q2.y*k2.y + q2.z*k2.z + q2.w*k2.w
                 + q3.x*k3.x + q3.y*k3.y + q3.z*k3.z + q3.w*k3.w;
        sc *= 0.25f;
        const float nm = fmaxf(m, sc);
        const float fold = __expf(m - nm);   // first iter: exp(-inf)=0
        const float es = __expf(sc - nm);
        denom = denom * fold + es;
        const float* vr = vp + s * 16;
        #pragma unroll
        for (int j = 0; j < 16; ++j)
            acc[j] = acc[j] * fold + es * vr[j];
        m = nm;
    }
    const float inv = 1.f / denom;
    float* op = Out + (size_t)n * NQ * 16 + l * 16;
    #pragma unroll
    for (int j = 0; j < 16; ++j) op[j] = acc[j] * inv;
}

// ---------------------------------------------------------------------------
// t = LayerNorm(elu(u)) * g + b ; rows of 2048, one block (256 thr) per row.
// jnp: mean/var population, eps 1e-5; elu alpha=1 (expm1).
// ---------------------------------------------------------------------------
__global__ __launch_bounds__(256)
void elu_ln_kernel(const float* __restrict__ U, const float* __restrict__ g,
                   const float* __restrict__ bb, float* __restrict__ Out)
{
    const int row = blockIdx.x;
    const float* up = U + (size_t)row * DFF;
    float* op = Out + (size_t)row * DFF;
    const int t = threadIdx.x;
    float vals[8];
    float s = 0.f, sq = 0.f;
    #pragma unroll
    for (int i = 0; i < 2; ++i) {
        const float4 x = *(const float4*)(up + (t << 2) + i * 1024);
        const float e0 = x.x > 0.f ? x.x : expm1f(x.x);
        const float e1 = x.y > 0.f ? x.y : expm1f(x.y);
        const float e2 = x.z > 0.f ? x.z : expm1f(x.z);
        const float e3 = x.w > 0.f ? x.w : expm1f(x.w);
        vals[i*4+0] = e0; vals[i*4+1] = e1; vals[i*4+2] = e2; vals[i*4+3] = e3;
        s  += e0 + e1 + e2 + e3;
        sq += e0*e0 + e1*e1 + e2*e2 + e3*e3;
    }
    #pragma unroll
    for (int off = 32; off > 0; off >>= 1) {
        s  += __shfl_xor(s,  off, 64);
        sq += __shfl_xor(sq, off, 64);
    }
    __shared__ float rs[4], rq[4];
    const int wave = t >> 6, lane = t & 63;
    if (lane == 0) { rs[wave] = s; rq[wave] = sq; }
    __syncthreads();
    const float ts = rs[0] + rs[1] + rs[2] + rs[3];
    const float tq = rq[0] + rq[1] + rq[2] + rq[3];
    const float mean = ts * (1.f / 2048.f);
    const float var  = tq * (1.f / 2048.f) - mean * mean;
    const float rinv = rsqrtf(var + 1e-5f);
    #pragma unroll
    for (int i = 0; i < 2; ++i) {
        const int idx = (t << 2) + i * 1024;
        const float4 g4 = *(const float4*)(g + idx);
        const float4 b4 = *(const float4*)(bb + idx);
        float4 o;
        o.x = (vals[i*4+0] - mean) * rinv * g4.x + b4.x;
        o.y = (vals[i*4+1] - mean) * rinv * g4.y + b4.y;
        o.z = (vals[i*4+2] - mean) * rinv * g4.z + b4.z;
        o.w = (vals[i*4+3] - mean) * rinv * g4.w + b4.w;
        *(float4*)(op + idx) = o;
    }
}

// ---------------------------------------------------------------------------
extern "C" void kernel_launch(void* const* d_in, const int* in_sizes, int n_in,
                              void* d_out, int out_size, void* d_ws, size_t ws_size,
                              hipStream_t stream)
{
    const float* x        = (const float*)d_in[0];
    const float* attn_q_w = (const float*)d_in[1];
    const float* attn_q_b = (const float*)d_in[2];
    const float* attn_k_w = (const float*)d_in[3];
    const float* attn_k_b = (const float*)d_in[4];
    const float* attn_v_w = (const float*)d_in[5];
    const float* attn_v_b = (const float*)d_in[6];
    const float* attn_o_w = (const float*)d_in[7];
    const float* attn_o_b = (const float*)d_in[8];
    const float* enc_w    = (const float*)d_in[9];
    const float* enc_b    = (const float*)d_in[10];
    const float* ff1_q_w  = (const float*)d_in[11];
    const float* ff1_q_b  = (const float*)d_in[12];
    const float* ff1_k_w  = (const float*)d_in[13];
    const float* ff1_k_b  = (const float*)d_in[14];
    const float* ff1_v_w  = (const float*)d_in[15];
    const float* ff1_v_b  = (const float*)d_in[16];
    const float* ff1_o_w  = (const float*)d_in[17];
    const float* ff1_o_b  = (const float*)d_in[18];
    const float* ff2_q_w  = (const float*)d_in[19];
    const float* ff2_q_b  = (const float*)d_in[20];
    const float* ff2_k_w  = (const float*)d_in[21];
    const float* ff2_k_b  = (const float*)d_in[22];
    const float* ff2_v_w  = (const float*)d_in[23];
    const float* ff2_v_b  = (const float*)d_in[24];
    const float* ff2_o_w  = (const float*)d_in[25];
    const float* ff2_o_b  = (const float*)d_in[26];
    const float* ln_g     = (const float*)d_in[27];
    const float* ln_b     = (const float*)d_in[28];
    (void)in_sizes; (void)n_in; (void)out_size; (void)ws_size;

    float* yout = (float*)d_out;                          // [20544, 512]
    float* Aout = yout + (size_t)N_ROWS * DD;             // [B,H,L,L] output A

    // Workspace: 3 small ([N,512]) + 3 large ([N,2048]) buffers = ~602 MB.
    const size_t NA = (size_t)N_ROWS * DD;
    const size_t NBg = (size_t)N_ROWS * DFF;
    float* ws = (float*)d_ws;
    float* A1 = ws;
    float* A2 = A1 + NA;
    float* A3 = A2 + NA;
    float* B1 = A3 + NA;
    float* B2 = B1 + NBg;
    float* B3 = B2 + NBg;

    const dim3 blk(256);
    const dim3 g512(N_ROWS / 64, DD / 64);    // 321 x 8
    const dim3 g2048(N_ROWS / 64, DFF / 64);  // 321 x 32

    // --- gattn ---
    sgemm_kernel<0,1,0><<<g512, blk, 0, stream>>>(x, attn_q_w, attn_q_b, nullptr, A1, N_ROWS, DD, DD);   // q=relu
    sgemm_kernel<0,0,0><<<g512, blk, 0, stream>>>(x, attn_k_w, attn_k_b, nullptr, A2, N_ROWS, DD, DD);   // k
    sgemm_kernel<0,1,0><<<g512, blk, 0, stream>>>(x, attn_v_w, attn_v_b, nullptr, A3, N_ROWS, DD, DD);   // v=relu
    scores_kernel<<<dim3(11, 11, BB * HH), blk, 0, stream>>>(A1, A2, Aout);
    topk_softmax_kernel<<<dim3((BB * HH * LSEQ) / 4), blk, 0, stream>>>(Aout);
    av_kernel<<<dim3(11, BB * HH), blk, 0, stream>>>(Aout, A3, A1);                                      // attn ctx -> A1
    sgemm_kernel<0,0,1><<<g512, blk, 0, stream>>>(A1, attn_o_w, attn_o_b, x, A2, N_ROWS, DD, DD);        // y = x + ctx@Wo+b
    // --- encoder proj (leaky pre-act fused) ---
    sgemm_kernel<2,0,0><<<g512, blk, 0, stream>>>(A2, enc_w, enc_b, nullptr, A3, N_ROWS, DD, DD);        // z
    // --- ff1 point-wise attention ---
    sgemm_kernel<0,1,0><<<g2048, blk, 0, stream>>>(A3, ff1_q_w, ff1_q_b, nullptr, B1, N_ROWS, DD, DFF);  // q1=relu
    sgemm_kernel<0,0,0><<<g512,  blk, 0, stream>>>(A3, ff1_k_w, ff1_k_b, nullptr, A1, N_ROWS, DD, DD);   // k1
    sgemm_kernel<0,1,0><<<g512,  blk, 0, stream>>>(A3, ff1_v_w, ff1_v_b, nullptr, A2, N_ROWS, DD, DD);   // v1=relu
    pw_attn_kernel<128,32><<<dim3((N_ROWS * 128) / 256), blk, 0, stream>>>(B1, A1, A2, B2);              // V1
    sgemm_kernel<0,0,1><<<g2048, blk, 0, stream>>>(B2, ff1_o_w, ff1_o_b, B1, B3, N_ROWS, DFF, DFF);      // u = q1 + V1@Wo+b
    elu_ln_kernel<<<dim3(N_ROWS), blk, 0, stream>>>(B3, ln_g, ln_b, B1);                                 // t
    // --- ff2 point-wise attention ---
    sgemm_kernel<0,1,0><<<g512,  blk, 0, stream>>>(B1, ff2_q_w, ff2_q_b, nullptr, A1, N_ROWS, DFF, DD);  // q2=relu
    sgemm_kernel<0,0,0><<<g2048, blk, 0, stream>>>(B1, ff2_k_w, ff2_k_b, nullptr, B2, N_ROWS, DFF, DFF); // k2
    sgemm_kernel<0,1,0><<<g2048, blk, 0, stream>>>(B1, ff2_v_w, ff2_v_b, nullptr, B3, N_ROWS, DFF, DFF); // v2=relu
    pw_attn_kernel<32,128><<<dim3((N_ROWS * 32) / 256), blk, 0, stream>>>(A1, B2, B3, A2);               // V2
    sgemm_kernel<0,0,1><<<g512, blk, 0, stream>>>(A2, ff2_o_w, ff2_o_b, A1, yout, N_ROWS, DD, DD);       // y_out = q2 + V2@Wo+b
}

// Round 2
// 3557.755 us; speedup vs baseline: 3.1105x; 3.1105x over previous
//
#include <hip/hip_runtime.h>
#include <hip/hip_bf16.h>
#include <math.h>

// Problem constants (B=64, L=321, D=512, DFF=2048, H=8, E=64, P=16, TOPK=10)
#define N_ROWS 20544   // B*L
#define MP     20608   // padded to 161*128 for MFMA tiles
#define LSEQ   321
#define BB     64
#define HH     8
#define EE     64
#define DD     512
#define DFF    2048

typedef __attribute__((ext_vector_type(8))) short bf16x8;
typedef __attribute__((ext_vector_type(4))) float f32x4;

__device__ inline float bf2f(unsigned short v){ unsigned u = ((unsigned)v) << 16; return __builtin_bit_cast(float, u); }
__device__ inline unsigned short f2bf(float f){ __hip_bfloat16 h = __float2bfloat16(f); return __builtin_bit_cast(unsigned short, h); }
__device__ inline float lo16(unsigned u){ return __builtin_bit_cast(float, u << 16); }
__device__ inline float hi16(unsigned u){ return __builtin_bit_cast(float, u & 0xffff0000u); }
__device__ inline unsigned packbf(float a, float b){ return (unsigned)f2bf(a) | ((unsigned)f2bf(b) << 16); }
__device__ inline void bf8_to_f(uint4 u, float* o){
    o[0]=lo16(u.x); o[1]=hi16(u.x); o[2]=lo16(u.y); o[3]=hi16(u.y);
    o[4]=lo16(u.z); o[5]=hi16(u.z); o[6]=lo16(u.w); o[7]=hi16(u.w);
}

#define GLDS16(gp, lp) __builtin_amdgcn_global_load_lds( \
    (const __attribute__((address_space(1))) unsigned int*)(gp), \
    (__attribute__((address_space(3))) unsigned int*)(lp), 16, 0, 0)

// ---------------------------------------------------------------------------
// FROZEN fp32 SGEMM (bit-identical to round 1) — used only for attn q/k/v so
// the scores -> topk boundary set (and thus output A) is unchanged.
// ---------------------------------------------------------------------------
template<int PRE, int POST, int RES>
__global__ __launch_bounds__(256)
void sgemm_kernel(const float* __restrict__ A, const float* __restrict__ W,
                  const float* __restrict__ bias, const float* __restrict__ R,
                  float* __restrict__ C, int M, int K, int N)
{
    __shared__ float As[16][68];
    __shared__ float Bs[16][64];
    const int t  = threadIdx.x;
    const int tx = t & 15, ty = t >> 4;
    const int row0 = blockIdx.x << 6, col0 = blockIdx.y << 6;
    const int ar = t >> 2;
    const int ak = (t & 3) << 2;
    const float* Ap = A + (size_t)(row0 + ar) * K + ak;
    const float* Wp = W + (size_t)ty * N + col0 + (tx << 2);
    float acc[4][4] = {};
    for (int k0 = 0; k0 < K; k0 += 16) {
        float4 av = *(const float4*)(Ap + k0);
        if (PRE == 2) {
            av.x = av.x >= 0.f ? av.x : 0.5f * av.x;
            av.y = av.y >= 0.f ? av.y : 0.5f * av.y;
            av.z = av.z >= 0.f ? av.z : 0.5f * av.z;
            av.w = av.w >= 0.f ? av.w : 0.5f * av.w;
        }
        float4 wv = *(const float4*)(Wp + (size_t)k0 * N);
        As[ak + 0][ar] = av.x;
        As[ak + 1][ar] = av.y;
        As[ak + 2][ar] = av.z;
        As[ak + 3][ar] = av.w;
        *(float4*)&Bs[ty][tx << 2] = wv;
        __syncthreads();
        #pragma unroll
        for (int kk = 0; kk < 16; ++kk) {
            const float4 a4 = *(const float4*)&As[kk][ty << 2];
            const float4 b4 = *(const float4*)&Bs[kk][tx << 2];
            const float a[4] = {a4.x, a4.y, a4.z, a4.w};
            const float b[4] = {b4.x, b4.y, b4.z, b4.w};
            #pragma unroll
            for (int i = 0; i < 4; ++i)
                #pragma unroll
                for (int j = 0; j < 4; ++j)
                    acc[i][j] = fmaf(a[i], b[j], acc[i][j]);
        }
        __syncthreads();
    }
    const float4 bi = *(const float4*)(bias + col0 + (tx << 2));
    #pragma unroll
    for (int i = 0; i < 4; ++i) {
        const int row = row0 + (ty << 2) + i;
        float4 c;
        c.x = acc[i][0] + bi.x;
        c.y = acc[i][1] + bi.y;
        c.z = acc[i][2] + bi.z;
        c.w = acc[i][3] + bi.w;
        if (RES) {
            const float4 r4 = *(const float4*)(R + (size_t)row * N + col0 + (tx << 2));
            c.x += r4.x; c.y += r4.y; c.z += r4.z; c.w += r4.w;
        }
        if (POST == 1) {
            c.x = fmaxf(c.x, 0.f); c.y = fmaxf(c.y, 0.f);
            c.z = fmaxf(c.z, 0.f); c.w = fmaxf(c.w, 0.f);
        }
        *(float4*)(C + (size_t)row * N + col0 + (tx << 2)) = c;
    }
}

// ---------------------------------------------------------------------------
// FROZEN: scores + topk/softmax (bit-identical to round 1)
// ---------------------------------------------------------------------------
__global__ __launch_bounds__(256)
void scores_kernel(const float* __restrict__ Q, const float* __restrict__ Kx,
                   float* __restrict__ Sc)
{
    const int bh = blockIdx.z, b = bh >> 3, h = bh & 7;
    const int l0 = blockIdx.x << 5, s0 = blockIdx.y << 5;
    __shared__ float qs[32][68];
    __shared__ float ks[32][68];
    const int t = threadIdx.x;
    #pragma unroll
    for (int pass = 0; pass < 2; ++pass) {
        const int r = (t >> 4) + (pass << 4);
        const int c = (t & 15) << 2;
        const int l = l0 + r, s = s0 + r;
        float4 qv = make_float4(0.f, 0.f, 0.f, 0.f);
        float4 kv = make_float4(0.f, 0.f, 0.f, 0.f);
        if (l < LSEQ) qv = *(const float4*)(Q + ((size_t)(b * LSEQ + l)) * DD + h * EE + c);
        if (s < LSEQ) kv = *(const float4*)(Kx + ((size_t)(b * LSEQ + s)) * DD + h * EE + c);
        *(float4*)&qs[r][c] = qv;
        *(float4*)&ks[r][c] = kv;
    }
    __syncthreads();
    const int sx = t & 31, ly = t >> 5;
    float accv[4] = {0.f, 0.f, 0.f, 0.f};
    for (int e = 0; e < EE; e += 4) {
        const float4 kv = *(const float4*)&ks[sx][e];
        #pragma unroll
        for (int i = 0; i < 4; ++i) {
            const float4 qv = *(const float4*)&qs[(ly << 2) + i][e];
            accv[i] += qv.x * kv.x + qv.y * kv.y + qv.z * kv.z + qv.w * kv.w;
        }
    }
    const int s = s0 + sx;
    if (s < LSEQ) {
        #pragma unroll
        for (int i = 0; i < 4; ++i) {
            const int l = l0 + (ly << 2) + i;
            if (l < LSEQ)
                Sc[((size_t)bh * LSEQ + l) * LSEQ + s] = accv[i];
        }
    }
}

__global__ __launch_bounds__(256)
void topk_softmax_kernel(float* __restrict__ S)
{
    const int wave = threadIdx.x >> 6;
    const int lane = threadIdx.x & 63;
    const size_t row = (size_t)blockIdx.x * 4 + wave;
    float* p = S + row * LSEQ;
    float v[6], w[6];
    #pragma unroll
    for (int j = 0; j < 6; ++j) {
        const int idx = lane + (j << 6);
        v[j] = (idx < LSEQ) ? p[idx] : -INFINITY;
        w[j] = v[j];
    }
    float gmax = 0.f, kth = 0.f;
    #pragma unroll
    for (int it = 0; it < 10; ++it) {
        float m = w[0];
        #pragma unroll
        for (int j = 1; j < 6; ++j) m = fmaxf(m, w[j]);
        #pragma unroll
        for (int off = 32; off > 0; off >>= 1)
            m = fmaxf(m, __shfl_xor(m, off, 64));
        if (it == 0) gmax = m;
        kth = m;
        if (it < 9) {
            int which = -1;
            #pragma unroll
            for (int j = 0; j < 6; ++j)
                if (which < 0 && w[j] == m) which = j;
            const unsigned long long msk = __ballot(which >= 0);
            const int first = __ffsll(msk) - 1;
            if (lane == first) {
                #pragma unroll
                for (int j = 0; j < 6; ++j)
                    if (j == which) w[j] = -INFINITY;
            }
        }
    }
    float ssum = 0.f;
    float e[6];
    #pragma unroll
    for (int j = 0; j < 6; ++j) {
        e[j] = (v[j] >= kth) ? __expf(0.125f * (v[j] - gmax)) : 0.f;
        ssum += e[j];
    }
    #pragma unroll
    for (int off = 32; off > 0; off >>= 1) ssum += __shfl_xor(ssum, off, 64);
    const float inv = 1.f / ssum;
    #pragma unroll
    for (int j = 0; j < 6; ++j) {
        const int idx = lane + (j << 6);
        if (idx < LSEQ) p[idx] = e[j] * inv;
    }
}

// ---------------------------------------------------------------------------
// A@V: same math as round 1, but stores ctx as bf16 (feeds MFMA attn_o GEMM).
// ---------------------------------------------------------------------------
__global__ __launch_bounds__(256)
void av_bf16_kernel(const float* __restrict__ A, const float* __restrict__ V,
                    unsigned short* __restrict__ Out)
{
    const int bh = blockIdx.y, b = bh >> 3, h = bh & 7;
    const int l0 = blockIdx.x << 5;
    __shared__ float As[32][36];
    __shared__ float Vs[32][68];
    const int t = threadIdx.x;
    const int tx = t & 15, ty = t >> 4;
    float acc[2][4] = {};
    for (int s0 = 0; s0 < LSEQ; s0 += 32) {
        {
            const int r = t >> 3, c = (t & 7) << 2;
            const int l = l0 + r;
            const float* ap = A + ((size_t)bh * LSEQ + (l < LSEQ ? l : 0)) * LSEQ + s0 + c;
            #pragma unroll
            for (int jj = 0; jj < 4; ++jj) {
                const int s = s0 + c + jj;
                As[r][c + jj] = (l < LSEQ && s < LSEQ) ? ap[jj] : 0.f;
            }
        }
        #pragma unroll
        for (int pass = 0; pass < 2; ++pass) {
            const int r = (t >> 4) + (pass << 4), c = (t & 15) << 2;
            const int s = s0 + r;
            float4 vv = make_float4(0.f, 0.f, 0.f, 0.f);
            if (s < LSEQ)
                vv = *(const float4*)(V + ((size_t)(b * LSEQ + s)) * DD + h * EE + c);
            *(float4*)&Vs[r][c] = vv;
        }
        __syncthreads();
        #pragma unroll
        for (int ss = 0; ss < 32; ++ss) {
            const float a0 = As[(ty << 1) + 0][ss];
            const float a1 = As[(ty << 1) + 1][ss];
            const float4 vv = *(const float4*)&Vs[ss][tx << 2];
            acc[0][0] = fmaf(a0, vv.x, acc[0][0]);
            acc[0][1] = fmaf(a0, vv.y, acc[0][1]);
            acc[0][2] = fmaf(a0, vv.z, acc[0][2]);
            acc[0][3] = fmaf(a0, vv.w, acc[0][3]);
            acc[1][0] = fmaf(a1, vv.x, acc[1][0]);
            acc[1][1] = fmaf(a1, vv.y, acc[1][1]);
            acc[1][2] = fmaf(a1, vv.z, acc[1][2]);
            acc[1][3] = fmaf(a1, vv.w, acc[1][3]);
        }
        __syncthreads();
    }
    #pragma unroll
    for (int i = 0; i < 2; ++i) {
        const int l = l0 + (ty << 1) + i;
        if (l < LSEQ) {
            ushort4 o;
            o.x = f2bf(acc[i][0]); o.y = f2bf(acc[i][1]);
            o.z = f2bf(acc[i][2]); o.w = f2bf(acc[i][3]);
            *(ushort4*)(Out + ((size_t)(b * LSEQ + l)) * DD + h * EE + (tx << 2)) = o;
        }
    }
}

// ---------------------------------------------------------------------------
// Weight prep: fp32 W[K][N] -> bf16 W^T[N][K] (one-time per launch, tiny)
// ---------------------------------------------------------------------------
__global__ __launch_bounds__(256)
void transpose_w_kernel(const float* __restrict__ W, unsigned short* __restrict__ Wt,
                        int K, int N)
{
    __shared__ unsigned short s[32][33];
    const int n0 = blockIdx.x << 5, k0 = blockIdx.y << 5;
    const int tx = threadIdx.x & 31, ty = threadIdx.x >> 5;
    #pragma unroll
    for (int i = 0; i < 32; i += 8)
        s[ty + i][tx] = f2bf(W[(size_t)(k0 + ty + i) * N + n0 + tx]);
    __syncthreads();
    #pragma unroll
    for (int i = 0; i < 32; i += 8)
        Wt[(size_t)(n0 + ty + i) * K + k0 + tx] = s[tx][ty + i];
}

// ---------------------------------------------------------------------------
// bf16 MFMA GEMM (m97 structure): C = POST(A@W + bias (+R))
// A: bf16 [Mp][K] row-major; Bt: bf16 [N][K] (pre-transposed weight).
// 128x128 block, 4 waves each 64x64 (4x4 of 16x16x32 MFMA), BK=32.
// LDS tiles [128][32] bf16, K-contiguous 16B frags -> bank-uniform b128 reads.
// Staged with global_load_lds width=16 (wave-uniform base + lane*16).
// RES: 0 none, 1 fp32 ptr, 2 bf16 ptr | POST: 0 none, 1 relu, 2 leaky(0.5)
// OUTBF: 1 bf16 out, 0 fp32 out. Requires N%128==0, K%32==0; M guarded.
// ---------------------------------------------------------------------------
template<int RES, int POST, int OUTBF>
__global__ __launch_bounds__(256)
void mgemm_kernel(const unsigned short* __restrict__ A, const unsigned short* __restrict__ Bt,
                  const float* __restrict__ bias, const void* __restrict__ Rres,
                  void* __restrict__ Cout, int M, int K, int N)
{
    __shared__ unsigned short As[128 * 32];
    __shared__ unsigned short Bs[128 * 32];
    const int t = threadIdx.x;
    const int lane = t & 63;
    const int wave = t >> 6;
    const int row0 = blockIdx.x << 7, col0 = blockIdx.y << 7;
    const int wm = (wave >> 1) << 6, wn = (wave & 1) << 6;
    // staging: granule g = t (rows 0..63) and 256+t (rows 64..127); 16B each
    const int r0 = t >> 2, kh = (t & 3) << 3;
    const unsigned short* Ag0 = A + (size_t)(row0 + r0) * K + kh;
    const unsigned short* Ag1 = Ag0 + (size_t)64 * K;
    const unsigned short* Bg0 = Bt + (size_t)(col0 + r0) * K + kh;
    const unsigned short* Bg1 = Bg0 + (size_t)64 * K;
    unsigned short* As0 = As + t * 8;  unsigned short* As1 = As0 + 2048;
    unsigned short* Bs0 = Bs + t * 8;  unsigned short* Bs1 = Bs0 + 2048;
    const int fm = lane & 15, fk = (lane >> 4) << 3;
    f32x4 acc[4][4] = {};
    for (int k0 = 0; k0 < K; k0 += 32) {
        GLDS16(Ag0 + k0, As0);
        GLDS16(Ag1 + k0, As1);
        GLDS16(Bg0 + k0, Bs0);
        GLDS16(Bg1 + k0, Bs1);
        __syncthreads();
        bf16x8 af[4], bfr[4];
        #pragma unroll
        for (int i = 0; i < 4; ++i) {
            af[i]  = *(const bf16x8*)(As + (wm + (i << 4) + fm) * 32 + fk);
            bfr[i] = *(const bf16x8*)(Bs + (wn + (i << 4) + fm) * 32 + fk);
        }
        #pragma unroll
        for (int i = 0; i < 4; ++i)
            #pragma unroll
            for (int j = 0; j < 4; ++j)
                acc[i][j] = __builtin_amdgcn_mfma_f32_16x16x32_bf16(af[i], bfr[j], acc[i][j], 0, 0, 0);
        __syncthreads();
    }
    // epilogue: C/D layout col=lane&15, row=(lane>>4)*4+reg [m89/m91]
    const int qr = (lane >> 4) << 2;
    #pragma unroll
    for (int j = 0; j < 4; ++j) {
        const int gcol = col0 + wn + (j << 4) + fm;
        const float bj = bias[gcol];
        #pragma unroll
        for (int i = 0; i < 4; ++i) {
            const int rb = row0 + wm + (i << 4) + qr;
            #pragma unroll
            for (int rg = 0; rg < 4; ++rg) {
                const int grow = rb + rg;
                if (grow < M) {
                    float c = acc[i][j][rg] + bj;
                    if (RES == 1) c += ((const float*)Rres)[(size_t)grow * N + gcol];
                    if (RES == 2) c += bf2f(((const unsigned short*)Rres)[(size_t)grow * N + gcol]);
                    if (POST == 1) c = fmaxf(c, 0.f);
                    if (POST == 2) c = c >= 0.f ? c : 0.5f * c;
                    if (OUTBF) ((unsigned short*)Cout)[(size_t)grow * N + gcol] = f2bf(c);
                    else       ((float*)Cout)[(size_t)grow * N + gcol] = c;
                }
            }
        }
    }
}

// ---------------------------------------------------------------------------
// Point-wise attention, bf16 in/out, fp32 math, online softmax.
// ---------------------------------------------------------------------------
template<int NQ, int NS>
__global__ __launch_bounds__(256)
void pw_attn_bf16(const unsigned short* __restrict__ Q, const unsigned short* __restrict__ Kx,
                  const unsigned short* __restrict__ V, unsigned short* __restrict__ Out)
{
    const long long gid = (long long)blockIdx.x * 256 + threadIdx.x;
    const long long n = gid / NQ;
    const int l = (int)(gid % NQ);
    float qf[16];
    {
        const uint4* qp = (const uint4*)(Q + (size_t)n * NQ * 16 + (size_t)l * 16);
        bf8_to_f(qp[0], qf); bf8_to_f(qp[1], qf + 8);
    }
    const unsigned short* kp = Kx + (size_t)n * NS * 16;
    const unsigned short* vp = V  + (size_t)n * NS * 16;
    float m = -INFINITY, denom = 0.f;
    float acc[16] = {};
    for (int s = 0; s < NS; ++s) {
        float kf[16], vf[16];
        const uint4* kr = (const uint4*)(kp + s * 16);
        bf8_to_f(kr[0], kf); bf8_to_f(kr[1], kf + 8);
        float sc = 0.f;
        #pragma unroll
        for (int j = 0; j < 16; ++j) sc = fmaf(qf[j], kf[j], sc);
        sc *= 0.25f;
        const float nm = fmaxf(m, sc);
        const float fold = __expf(m - nm);
        const float es = __expf(sc - nm);
        denom = denom * fold + es;
        const uint4* vr = (const uint4*)(vp + s * 16);
        bf8_to_f(vr[0], vf); bf8_to_f(vr[1], vf + 8);
        #pragma unroll
        for (int j = 0; j < 16; ++j) acc[j] = acc[j] * fold + es * vf[j];
        m = nm;
    }
    const float inv = 1.f / denom;
    uint4 o0, o1;
    o0.x = packbf(acc[0] * inv,  acc[1] * inv);
    o0.y = packbf(acc[2] * inv,  acc[3] * inv);
    o0.z = packbf(acc[4] * inv,  acc[5] * inv);
    o0.w = packbf(acc[6] * inv,  acc[7] * inv);
    o1.x = packbf(acc[8] * inv,  acc[9] * inv);
    o1.y = packbf(acc[10] * inv, acc[11] * inv);
    o1.z = packbf(acc[12] * inv, acc[13] * inv);
    o1.w = packbf(acc[14] * inv, acc[15] * inv);
    uint4* op = (uint4*)(Out + (size_t)n * NQ * 16 + (size_t)l * 16);
    op[0] = o0; op[1] = o1;
}

// ---------------------------------------------------------------------------
// t = LayerNorm(elu(u)) * g + b ; bf16 in / bf16 out, fp32 math.
// One 256-thread block per row of 2048; thread handles 8 contiguous elems.
// ---------------------------------------------------------------------------
__global__ __launch_bounds__(256)
void elu_ln_bf16_kernel(const unsigned short* __restrict__ U, const float* __restrict__ g,
                        const float* __restrict__ bb, unsigned short* __restrict__ Out)
{
    const int row = blockIdx.x;
    const int t = threadIdx.x;
    const size_t base = (size_t)row * DFF + (size_t)t * 8;
    float vals[8];
    {
        const uint4 u4 = *(const uint4*)(U + base);
        bf8_to_f(u4, vals);
    }
    float s = 0.f, sq = 0.f;
    #pragma unroll
    for (int j = 0; j < 8; ++j) {
        const float e = vals[j] > 0.f ? vals[j] : expm1f(vals[j]);
        vals[j] = e;
        s += e; sq += e * e;
    }
    #pragma unroll
    for (int off = 32; off > 0; off >>= 1) {
        s  += __shfl_xor(s,  off, 64);
        sq += __shfl_xor(sq, off, 64);
    }
    __shared__ float rs[4], rq[4];
    const int wave = t >> 6, lane = t & 63;
    if (lane == 0) { rs[wave] = s; rq[wave] = sq; }
    __syncthreads();
    const float ts = rs[0] + rs[1] + rs[2] + rs[3];
    const float tq = rq[0] + rq[1] + rq[2] + rq[3];
    const float mean = ts * (1.f / 2048.f);
    const float var  = tq * (1.f / 2048.f) - mean * mean;
    const float rinv = rsqrtf(var + 1e-5f);
    const float4 g0 = *(const float4*)(g + t * 8);
    const float4 g1 = *(const float4*)(g + t * 8 + 4);
    const float4 b0 = *(const float4*)(bb + t * 8);
    const float4 b1 = *(const float4*)(bb + t * 8 + 4);
    float o[8];
    o[0] = (vals[0] - mean) * rinv * g0.x + b0.x;
    o[1] = (vals[1] - mean) * rinv * g0.y + b0.y;
    o[2] = (vals[2] - mean) * rinv * g0.z + b0.z;
    o[3] = (vals[3] - mean) * rinv * g0.w + b0.w;
    o[4] = (vals[4] - mean) * rinv * g1.x + b1.x;
    o[5] = (vals[5] - mean) * rinv * g1.y + b1.y;
    o[6] = (vals[6] - mean) * rinv * g1.z + b1.z;
    o[7] = (vals[7] - mean) * rinv * g1.w + b1.w;
    uint4 ov;
    ov.x = packbf(o[0], o[1]); ov.y = packbf(o[2], o[3]);
    ov.z = packbf(o[4], o[5]); ov.w = packbf(o[6], o[7]);
    *(uint4*)(Out + base) = ov;
}

// ---------------------------------------------------------------------------
extern "C" void kernel_launch(void* const* d_in, const int* in_sizes, int n_in,
                              void* d_out, int out_size, void* d_ws, size_t ws_size,
                              hipStream_t stream)
{
    const float* x        = (const float*)d_in[0];
    const float* attn_q_w = (const float*)d_in[1];
    const float* attn_q_b = (const float*)d_in[2];
    const float* attn_k_w = (const float*)d_in[3];
    const float* attn_k_b = (const float*)d_in[4];
    const float* attn_v_w = (const float*)d_in[5];
    const float* attn_v_b = (const float*)d_in[6];
    const float* attn_o_w = (const float*)d_in[7];
    const float* attn_o_b = (const float*)d_in[8];
    const float* enc_w    = (const float*)d_in[9];
    const float* enc_b    = (const float*)d_in[10];
    const float* ff1_q_w  = (const float*)d_in[11];
    const float* ff1_q_b  = (const float*)d_in[12];
    const float* ff1_k_w  = (const float*)d_in[13];
    const float* ff1_k_b  = (const float*)d_in[14];
    const float* ff1_v_w  = (const float*)d_in[15];
    const float* ff1_v_b  = (const float*)d_in[16];
    const float* ff1_o_w  = (const float*)d_in[17];
    const float* ff1_o_b  = (const float*)d_in[18];
    const float* ff2_q_w  = (const float*)d_in[19];
    const float* ff2_q_b  = (const float*)d_in[20];
    const float* ff2_k_w  = (const float*)d_in[21];
    const float* ff2_k_b  = (const float*)d_in[22];
    const float* ff2_v_w  = (const float*)d_in[23];
    const float* ff2_v_b  = (const float*)d_in[24];
    const float* ff2_o_w  = (const float*)d_in[25];
    const float* ff2_o_b  = (const float*)d_in[26];
    const float* ln_g     = (const float*)d_in[27];
    const float* ln_b     = (const float*)d_in[28];
    (void)in_sizes; (void)n_in; (void)out_size; (void)ws_size;

    float* yout = (float*)d_out;                      // [20544, 512] fp32
    float* Aout = yout + (size_t)N_ROWS * DD;         // [B,H,L,L] fp32

    // ---- workspace carve (≈453 MiB) ----
    char* cur = (char*)d_ws;
    auto alloc = [&](size_t bytes) -> void* {
        void* p = (void*)cur;
        cur += (bytes + 255) & ~(size_t)255;
        return p;
    };
    const size_t F32S = (size_t)N_ROWS * DD * 4;      // fp32 [N,512]
    const size_t BFS  = (size_t)MP * DD * 2;          // bf16 [MP,512]
    const size_t BFG  = (size_t)MP * DFF * 2;         // bf16 [MP,2048]
    float* A1 = (float*)alloc(F32S);                  // q (frozen fp32)
    float* A2 = (float*)alloc(F32S);                  // k
    float* A3 = (float*)alloc(F32S);                  // v
    unsigned short* S1 = (unsigned short*)alloc(BFS); // ctx -> z -> q2
    unsigned short* S2 = (unsigned short*)alloc(BFS); // ly -> k1 -> V2
    unsigned short* S3 = (unsigned short*)alloc(BFS); // v1
    unsigned short* G1 = (unsigned short*)alloc(BFG); // q1 -> t
    unsigned short* G2 = (unsigned short*)alloc(BFG); // V1 -> k2
    unsigned short* G3 = (unsigned short*)alloc(BFG); // u  -> v2
    unsigned short* wt_ao  = (unsigned short*)alloc((size_t)DD * DD * 2);
    unsigned short* wt_enc = (unsigned short*)alloc((size_t)DD * DD * 2);
    unsigned short* wt_f1q = (unsigned short*)alloc((size_t)DFF * DD * 2);
    unsigned short* wt_f1k = (unsigned short*)alloc((size_t)DD * DD * 2);
    unsigned short* wt_f1v = (unsigned short*)alloc((size_t)DD * DD * 2);
    unsigned short* wt_f1o = (unsigned short*)alloc((size_t)DFF * DFF * 2);
    unsigned short* wt_f2q = (unsigned short*)alloc((size_t)DD * DFF * 2);
    unsigned short* wt_f2k = (unsigned short*)alloc((size_t)DFF * DFF * 2);
    unsigned short* wt_f2v = (unsigned short*)alloc((size_t)DFF * DFF * 2);
    unsigned short* wt_f2o = (unsigned short*)alloc((size_t)DD * DD * 2);

    const dim3 blk(256);
    const dim3 g512(N_ROWS / 64, DD / 64);            // frozen fp32 grid
    const dim3 gm512(MP / 128, DD / 128);             // 161 x 4
    const dim3 gm2048(MP / 128, DFF / 128);           // 161 x 16

    // ---- weight prep (bf16, transposed [N][K]) ----
    transpose_w_kernel<<<dim3(DD/32,  DD/32),  blk, 0, stream>>>(attn_o_w, wt_ao,  DD,  DD);
    transpose_w_kernel<<<dim3(DD/32,  DD/32),  blk, 0, stream>>>(enc_w,    wt_enc, DD,  DD);
    transpose_w_kernel<<<dim3(DFF/32, DD/32),  blk, 0, stream>>>(ff1_q_w,  wt_f1q, DD,  DFF);
    transpose_w_kernel<<<dim3(DD/32,  DD/32),  blk, 0, stream>>>(ff1_k_w,  wt_f1k, DD,  DD);
    transpose_w_kernel<<<dim3(DD/32,  DD/32),  blk, 0, stream>>>(ff1_v_w,  wt_f1v, DD,  DD);
    transpose_w_kernel<<<dim3(DFF/32, DFF/32), blk, 0, stream>>>(ff1_o_w,  wt_f1o, DFF, DFF);
    transpose_w_kernel<<<dim3(DD/32,  DFF/32), blk, 0, stream>>>(ff2_q_w,  wt_f2q, DFF, DD);
    transpose_w_kernel<<<dim3(DFF/32, DFF/32), blk, 0, stream>>>(ff2_k_w,  wt_f2k, DFF, DFF);
    transpose_w_kernel<<<dim3(DFF/32, DFF/32), blk, 0, stream>>>(ff2_v_w,  wt_f2v, DFF, DFF);
    transpose_w_kernel<<<dim3(DD/32,  DD/32),  blk, 0, stream>>>(ff2_o_w,  wt_f2o, DD,  DD);

    // ---- gattn (A path FROZEN fp32 for bit-identical topk) ----
    sgemm_kernel<0,1,0><<<g512, blk, 0, stream>>>(x, attn_q_w, attn_q_b, nullptr, A1, N_ROWS, DD, DD);
    sgemm_kernel<0,0,0><<<g512, blk, 0, stream>>>(x, attn_k_w, attn_k_b, nullptr, A2, N_ROWS, DD, DD);
    sgemm_kernel<0,1,0><<<g512, blk, 0, stream>>>(x, attn_v_w, attn_v_b, nullptr, A3, N_ROWS, DD, DD);
    scores_kernel<<<dim3(11, 11, BB * HH), blk, 0, stream>>>(A1, A2, Aout);
    topk_softmax_kernel<<<dim3((BB * HH * LSEQ) / 4), blk, 0, stream>>>(Aout);
    av_bf16_kernel<<<dim3(11, BB * HH), blk, 0, stream>>>(Aout, A3, S1);                       // ctx bf16

    // ---- y path, all bf16 MFMA ----
    mgemm_kernel<1,2,1><<<gm512, blk, 0, stream>>>(S1, wt_ao, attn_o_b, x, S2, N_ROWS, DD, DD);     // ly = leaky(x+ctx@Wo+b)
    mgemm_kernel<0,0,1><<<gm512, blk, 0, stream>>>(S2, wt_enc, enc_b, nullptr, S1, N_ROWS, DD, DD); // z
    mgemm_kernel<0,1,1><<<gm2048, blk, 0, stream>>>(S1, wt_f1q, ff1_q_b, nullptr, G1, N_ROWS, DD, DFF); // q1
    mgemm_kernel<0,0,1><<<gm512, blk, 0, stream>>>(S1, wt_f1k, ff1_k_b, nullptr, S2, N_ROWS, DD, DD);   // k1
    mgemm_kernel<0,1,1><<<gm512, blk, 0, stream>>>(S1, wt_f1v, ff1_v_b, nullptr, S3, N_ROWS, DD, DD);   // v1
    pw_attn_bf16<128,32><<<dim3((N_ROWS * 128) / 256), blk, 0, stream>>>(G1, S2, S3, G2);               // V1
    mgemm_kernel<2,0,1><<<gm2048, blk, 0, stream>>>(G2, wt_f1o, ff1_o_b, G1, G3, N_ROWS, DFF, DFF);     // u = q1 + V1@Wo+b
    elu_ln_bf16_kernel<<<dim3(N_ROWS), blk, 0, stream>>>(G3, ln_g, ln_b, G1);                           // t
    mgemm_kernel<0,1,1><<<gm512, blk, 0, stream>>>(G1, wt_f2q, ff2_q_b, nullptr, S1, N_ROWS, DFF, DD);  // q2
    mgemm_kernel<0,0,1><<<gm2048, blk, 0, stream>>>(G1, wt_f2k, ff2_k_b, nullptr, G2, N_ROWS, DFF, DFF);// k2
    mgemm_kernel<0,1,1><<<gm2048, blk, 0, stream>>>(G1, wt_f2v, ff2_v_b, nullptr, G3, N_ROWS, DFF, DFF);// v2
    pw_attn_bf16<32,128><<<dim3((N_ROWS * 32) / 256), blk, 0, stream>>>(S1, G2, G3, S2);                // V2
    mgemm_kernel<2,0,0><<<gm512, blk, 0, stream>>>(S2, wt_f2o, ff2_o_b, S1, yout, N_ROWS, DD, DD);      // yout fp32
}

// Round 3
// 3085.620 us; speedup vs baseline: 3.5864x; 1.1530x over previous
//
#include <hip/hip_runtime.h>
#include <hip/hip_bf16.h>
#include <math.h>

// Problem constants (B=64, L=321, D=512, DFF=2048, H=8, E=64, P=16, TOPK=10)
#define N_ROWS 20544   // B*L
#define MP     20608   // padded to 161*128 for MFMA tiles
#define LSEQ   321
#define BB     64
#define HH     8
#define EE     64
#define DD     512
#define DFF    2048

typedef __attribute__((ext_vector_type(8))) short bf16x8;
typedef __attribute__((ext_vector_type(4))) float f32x4;

__device__ inline float bf2f(unsigned short v){ unsigned u = ((unsigned)v) << 16; return __builtin_bit_cast(float, u); }
__device__ inline unsigned short f2bf(float f){ __hip_bfloat16 h = __float2bfloat16(f); return __builtin_bit_cast(unsigned short, h); }
__device__ inline float lo16(unsigned u){ return __builtin_bit_cast(float, u << 16); }
__device__ inline float hi16(unsigned u){ return __builtin_bit_cast(float, u & 0xffff0000u); }
__device__ inline unsigned packbf(float a, float b){ return (unsigned)f2bf(a) | ((unsigned)f2bf(b) << 16); }
__device__ inline void bf8_to_f(uint4 u, float* o){
    o[0]=lo16(u.x); o[1]=hi16(u.x); o[2]=lo16(u.y); o[3]=hi16(u.y);
    o[4]=lo16(u.z); o[5]=hi16(u.z); o[6]=lo16(u.w); o[7]=hi16(u.w);
}

#define GLDS16(gp, lp) __builtin_amdgcn_global_load_lds( \
    (const __attribute__((address_space(1))) unsigned int*)(gp), \
    (__attribute__((address_space(3))) unsigned int*)(lp), 16, 0, 0)

// ---------------------------------------------------------------------------
// fp32 GEMM for q,k (feeds frozen scores->topk). 128x64 tile, 8x4 micro.
// Each output is a single fmaf chain over ascending k — bit-identical math
// to rounds 1/2. POST: 0 none, 1 relu.
// ---------------------------------------------------------------------------
template<int POST>
__global__ __launch_bounds__(256)
void sgemm128_kernel(const float* __restrict__ A, const float* __restrict__ W,
                     const float* __restrict__ bias, float* __restrict__ C,
                     int M, int K, int N)
{
    __shared__ float As[16][132];   // [k][row], 128 rows + pad
    __shared__ float Bs[16][64];    // [k][col]
    const int t  = threadIdx.x;
    const int tx = t & 15, ty = t >> 4;
    const int row0 = blockIdx.x << 7, col0 = blockIdx.y << 6;
    const int ar = t >> 2;          // 0..63
    const int ak = (t & 3) << 2;    // 0,4,8,12
    const float* Wp = W + (size_t)ty * N + col0 + (tx << 2);
    float acc[8][4] = {};
    for (int k0 = 0; k0 < K; k0 += 16) {
        float4 a0 = make_float4(0.f,0.f,0.f,0.f);
        float4 a1 = make_float4(0.f,0.f,0.f,0.f);
        if (row0 + ar < M)      a0 = *(const float4*)(A + (size_t)(row0 + ar) * K + k0 + ak);
        if (row0 + ar + 64 < M) a1 = *(const float4*)(A + (size_t)(row0 + ar + 64) * K + k0 + ak);
        const float4 wv = *(const float4*)(Wp + (size_t)k0 * N);
        As[ak + 0][ar] = a0.x; As[ak + 1][ar] = a0.y;
        As[ak + 2][ar] = a0.z; As[ak + 3][ar] = a0.w;
        As[ak + 0][ar + 64] = a1.x; As[ak + 1][ar + 64] = a1.y;
        As[ak + 2][ar + 64] = a1.z; As[ak + 3][ar + 64] = a1.w;
        *(float4*)&Bs[ty][tx << 2] = wv;
        __syncthreads();
        #pragma unroll
        for (int kk = 0; kk < 16; ++kk) {
            const float4 aA = *(const float4*)&As[kk][ty << 3];
            const float4 aB = *(const float4*)&As[kk][(ty << 3) + 4];
            const float4 b4 = *(const float4*)&Bs[kk][tx << 2];
            const float a[8] = {aA.x, aA.y, aA.z, aA.w, aB.x, aB.y, aB.z, aB.w};
            const float b[4] = {b4.x, b4.y, b4.z, b4.w};
            #pragma unroll
            for (int i = 0; i < 8; ++i)
                #pragma unroll
                for (int j = 0; j < 4; ++j)
                    acc[i][j] = fmaf(a[i], b[j], acc[i][j]);
        }
        __syncthreads();
    }
    const float4 bi = *(const float4*)(bias + col0 + (tx << 2));
    #pragma unroll
    for (int i = 0; i < 8; ++i) {
        const int row = row0 + (ty << 3) + i;
        if (row < M) {
            float4 c;
            c.x = acc[i][0] + bi.x;
            c.y = acc[i][1] + bi.y;
            c.z = acc[i][2] + bi.z;
            c.w = acc[i][3] + bi.w;
            if (POST == 1) {
                c.x = fmaxf(c.x, 0.f); c.y = fmaxf(c.y, 0.f);
                c.z = fmaxf(c.z, 0.f); c.w = fmaxf(c.w, 0.f);
            }
            *(float4*)(C + (size_t)row * N + col0 + (tx << 2)) = c;
        }
    }
}

// ---------------------------------------------------------------------------
// scores[b,h,l,s] = sum_e q[.] * k[.]  — 64x64 tile, 4x4 strided micro.
// Inner expression is a textual copy of round 1 (same FP contraction).
// grid: (6, 6, B*H)
// ---------------------------------------------------------------------------
__global__ __launch_bounds__(256)
void scores64_kernel(const float* __restrict__ Q, const float* __restrict__ Kx,
                     float* __restrict__ Sc)
{
    const int bh = blockIdx.z, b = bh >> 3, h = bh & 7;
    const int l0 = blockIdx.x << 6, s0 = blockIdx.y << 6;
    __shared__ float qs[64][68];
    __shared__ float ks[64][68];
    const int t = threadIdx.x;
    {
        const int r = t >> 4;           // 0..15
        const int c = (t & 15) << 2;    // 0..60
        #pragma unroll
        for (int i = 0; i < 4; ++i) {
            const int rr = r + (i << 4);
            const int l = l0 + rr, s = s0 + rr;
            float4 qv = make_float4(0.f, 0.f, 0.f, 0.f);
            float4 kv = make_float4(0.f, 0.f, 0.f, 0.f);
            if (l < LSEQ) qv = *(const float4*)(Q + ((size_t)(b * LSEQ + l)) * DD + h * EE + c);
            if (s < LSEQ) kv = *(const float4*)(Kx + ((size_t)(b * LSEQ + s)) * DD + h * EE + c);
            *(float4*)&qs[rr][c] = qv;
            *(float4*)&ks[rr][c] = kv;
        }
    }
    __syncthreads();
    const int tx = t & 15, ty = t >> 4;
    float acc[4][4] = {};
    for (int e = 0; e < EE; e += 4) {
        float4 q4[4], k4[4];
        #pragma unroll
        for (int i = 0; i < 4; ++i) q4[i] = *(const float4*)&qs[ty + (i << 4)][e];
        #pragma unroll
        for (int j = 0; j < 4; ++j) k4[j] = *(const float4*)&ks[tx + (j << 4)][e];
        #pragma unroll
        for (int i = 0; i < 4; ++i)
            #pragma unroll
            for (int j = 0; j < 4; ++j)
                acc[i][j] += q4[i].x * k4[j].x + q4[i].y * k4[j].y + q4[i].z * k4[j].z + q4[i].w * k4[j].w;
    }
    #pragma unroll
    for (int i = 0; i < 4; ++i) {
        const int l = l0 + ty + (i << 4);
        if (l < LSEQ) {
            #pragma unroll
            for (int j = 0; j < 4; ++j) {
                const int s = s0 + tx + (j << 4);
                if (s < LSEQ)
                    Sc[((size_t)bh * LSEQ + l) * LSEQ + s] = acc[i][j];
            }
        }
    }
}

// ---------------------------------------------------------------------------
// FROZEN: topk/softmax (bit-identical to round 1)
// ---------------------------------------------------------------------------
__global__ __launch_bounds__(256)
void topk_softmax_kernel(float* __restrict__ S)
{
    const int wave = threadIdx.x >> 6;
    const int lane = threadIdx.x & 63;
    const size_t row = (size_t)blockIdx.x * 4 + wave;
    float* p = S + row * LSEQ;
    float v[6], w[6];
    #pragma unroll
    for (int j = 0; j < 6; ++j) {
        const int idx = lane + (j << 6);
        v[j] = (idx < LSEQ) ? p[idx] : -INFINITY;
        w[j] = v[j];
    }
    float gmax = 0.f, kth = 0.f;
    #pragma unroll
    for (int it = 0; it < 10; ++it) {
        float m = w[0];
        #pragma unroll
        for (int j = 1; j < 6; ++j) m = fmaxf(m, w[j]);
        #pragma unroll
        for (int off = 32; off > 0; off >>= 1)
            m = fmaxf(m, __shfl_xor(m, off, 64));
        if (it == 0) gmax = m;
        kth = m;
        if (it < 9) {
            int which = -1;
            #pragma unroll
            for (int j = 0; j < 6; ++j)
                if (which < 0 && w[j] == m) which = j;
            const unsigned long long msk = __ballot(which >= 0);
            const int first = __ffsll(msk) - 1;
            if (lane == first) {
                #pragma unroll
                for (int j = 0; j < 6; ++j)
                    if (j == which) w[j] = -INFINITY;
            }
        }
    }
    float ssum = 0.f;
    float e[6];
    #pragma unroll
    for (int j = 0; j < 6; ++j) {
        e[j] = (v[j] >= kth) ? __expf(0.125f * (v[j] - gmax)) : 0.f;
        ssum += e[j];
    }
    #pragma unroll
    for (int off = 32; off > 0; off >>= 1) ssum += __shfl_xor(ssum, off, 64);
    const float inv = 1.f / ssum;
    #pragma unroll
    for (int j = 0; j < 6; ++j) {
        const int idx = lane + (j << 6);
        if (idx < LSEQ) p[idx] = e[j] * inv;
    }
}

// ---------------------------------------------------------------------------
// A@V: A fp32 (softmax weights), V bf16; ctx out bf16.
// ---------------------------------------------------------------------------
__global__ __launch_bounds__(256)
void av_bf16_kernel(const float* __restrict__ A, const unsigned short* __restrict__ V,
                    unsigned short* __restrict__ Out)
{
    const int bh = blockIdx.y, b = bh >> 3, h = bh & 7;
    const int l0 = blockIdx.x << 5;
    __shared__ float As[32][36];
    __shared__ float Vs[32][68];
    const int t = threadIdx.x;
    const int tx = t & 15, ty = t >> 4;
    float acc[2][4] = {};
    for (int s0 = 0; s0 < LSEQ; s0 += 32) {
        {
            const int r = t >> 3, c = (t & 7) << 2;
            const int l = l0 + r;
            const float* ap = A + ((size_t)bh * LSEQ + (l < LSEQ ? l : 0)) * LSEQ + s0 + c;
            #pragma unroll
            for (int jj = 0; jj < 4; ++jj) {
                const int s = s0 + c + jj;
                As[r][c + jj] = (l < LSEQ && s < LSEQ) ? ap[jj] : 0.f;
            }
        }
        #pragma unroll
        for (int pass = 0; pass < 2; ++pass) {
            const int r = (t >> 4) + (pass << 4), c = (t & 15) << 2;
            const int s = s0 + r;
            float4 vv = make_float4(0.f, 0.f, 0.f, 0.f);
            if (s < LSEQ) {
                const ushort4 u = *(const ushort4*)(V + ((size_t)(b * LSEQ + s)) * DD + h * EE + c);
                vv.x = bf2f(u.x); vv.y = bf2f(u.y); vv.z = bf2f(u.z); vv.w = bf2f(u.w);
            }
            *(float4*)&Vs[r][c] = vv;
        }
        __syncthreads();
        #pragma unroll
        for (int ss = 0; ss < 32; ++ss) {
            const float a0 = As[(ty << 1) + 0][ss];
            const float a1 = As[(ty << 1) + 1][ss];
            const float4 vv = *(const float4*)&Vs[ss][tx << 2];
            acc[0][0] = fmaf(a0, vv.x, acc[0][0]);
            acc[0][1] = fmaf(a0, vv.y, acc[0][1]);
            acc[0][2] = fmaf(a0, vv.z, acc[0][2]);
            acc[0][3] = fmaf(a0, vv.w, acc[0][3]);
            acc[1][0] = fmaf(a1, vv.x, acc[1][0]);
            acc[1][1] = fmaf(a1, vv.y, acc[1][1]);
            acc[1][2] = fmaf(a1, vv.z, acc[1][2]);
            acc[1][3] = fmaf(a1, vv.w, acc[1][3]);
        }
        __syncthreads();
    }
    #pragma unroll
    for (int i = 0; i < 2; ++i) {
        const int l = l0 + (ty << 1) + i;
        if (l < LSEQ) {
            ushort4 o;
            o.x = f2bf(acc[i][0]); o.y = f2bf(acc[i][1]);
            o.z = f2bf(acc[i][2]); o.w = f2bf(acc[i][3]);
            *(ushort4*)(Out + ((size_t)(b * LSEQ + l)) * DD + h * EE + (tx << 2)) = o;
        }
    }
}

// ---------------------------------------------------------------------------
// fp32 -> bf16 convert (x staging for MFMA); pads tail rows with zeros.
// ---------------------------------------------------------------------------
__global__ __launch_bounds__(256)
void f32_to_bf16_kernel(const float* __restrict__ X, unsigned short* __restrict__ Y,
                        long long nvalid, long long ntotal)
{
    const long long i = ((long long)blockIdx.x * 256 + threadIdx.x) * 4;
    if (i >= ntotal) return;
    float4 v = make_float4(0.f, 0.f, 0.f, 0.f);
    if (i < nvalid) v = *(const float4*)(X + i);
    ushort4 o;
    o.x = f2bf(v.x); o.y = f2bf(v.y); o.z = f2bf(v.z); o.w = f2bf(v.w);
    *(ushort4*)(Y + i) = o;
}

// ---------------------------------------------------------------------------
// Weight prep: fp32 W[K][N] -> bf16 W^T[N][K]
// ---------------------------------------------------------------------------
__global__ __launch_bounds__(256)
void transpose_w_kernel(const float* __restrict__ W, unsigned short* __restrict__ Wt,
                        int K, int N)
{
    __shared__ unsigned short s[32][33];
    const int n0 = blockIdx.x << 5, k0 = blockIdx.y << 5;
    const int tx = threadIdx.x & 31, ty = threadIdx.x >> 5;
    #pragma unroll
    for (int i = 0; i < 32; i += 8)
        s[ty + i][tx] = f2bf(W[(size_t)(k0 + ty + i) * N + n0 + tx]);
    __syncthreads();
    #pragma unroll
    for (int i = 0; i < 32; i += 8)
        Wt[(size_t)(n0 + ty + i) * K + k0 + tx] = s[tx][ty + i];
}

// ---------------------------------------------------------------------------
// bf16 MFMA GEMM (m97 structure) — unchanged from round 2.
// ---------------------------------------------------------------------------
template<int RES, int POST, int OUTBF>
__global__ __launch_bounds__(256)
void mgemm_kernel(const unsigned short* __restrict__ A, const unsigned short* __restrict__ Bt,
                  const float* __restrict__ bias, const void* __restrict__ Rres,
                  void* __restrict__ Cout, int M, int K, int N)
{
    __shared__ unsigned short As[128 * 32];
    __shared__ unsigned short Bs[128 * 32];
    const int t = threadIdx.x;
    const int lane = t & 63;
    const int wave = t >> 6;
    const int row0 = blockIdx.x << 7, col0 = blockIdx.y << 7;
    const int wm = (wave >> 1) << 6, wn = (wave & 1) << 6;
    const int r0 = t >> 2, kh = (t & 3) << 3;
    const unsigned short* Ag0 = A + (size_t)(row0 + r0) * K + kh;
    const unsigned short* Ag1 = Ag0 + (size_t)64 * K;
    const unsigned short* Bg0 = Bt + (size_t)(col0 + r0) * K + kh;
    const unsigned short* Bg1 = Bg0 + (size_t)64 * K;
    unsigned short* As0 = As + t * 8;  unsigned short* As1 = As0 + 2048;
    unsigned short* Bs0 = Bs + t * 8;  unsigned short* Bs1 = Bs0 + 2048;
    const int fm = lane & 15, fk = (lane >> 4) << 3;
    f32x4 acc[4][4] = {};
    for (int k0 = 0; k0 < K; k0 += 32) {
        GLDS16(Ag0 + k0, As0);
        GLDS16(Ag1 + k0, As1);
        GLDS16(Bg0 + k0, Bs0);
        GLDS16(Bg1 + k0, Bs1);
        __syncthreads();
        bf16x8 af[4], bfr[4];
        #pragma unroll
        for (int i = 0; i < 4; ++i) {
            af[i]  = *(const bf16x8*)(As + (wm + (i << 4) + fm) * 32 + fk);
            bfr[i] = *(const bf16x8*)(Bs + (wn + (i << 4) + fm) * 32 + fk);
        }
        #pragma unroll
        for (int i = 0; i < 4; ++i)
            #pragma unroll
            for (int j = 0; j < 4; ++j)
                acc[i][j] = __builtin_amdgcn_mfma_f32_16x16x32_bf16(af[i], bfr[j], acc[i][j], 0, 0, 0);
        __syncthreads();
    }
    const int qr = (lane >> 4) << 2;
    #pragma unroll
    for (int j = 0; j < 4; ++j) {
        const int gcol = col0 + wn + (j << 4) + fm;
        const float bj = bias[gcol];
        #pragma unroll
        for (int i = 0; i < 4; ++i) {
            const int rb = row0 + wm + (i << 4) + qr;
            #pragma unroll
            for (int rg = 0; rg < 4; ++rg) {
                const int grow = rb + rg;
                if (grow < M) {
                    float c = acc[i][j][rg] + bj;
                    if (RES == 1) c += ((const float*)Rres)[(size_t)grow * N + gcol];
                    if (RES == 2) c += bf2f(((const unsigned short*)Rres)[(size_t)grow * N + gcol]);
                    if (POST == 1) c = fmaxf(c, 0.f);
                    if (POST == 2) c = c >= 0.f ? c : 0.5f * c;
                    if (OUTBF) ((unsigned short*)Cout)[(size_t)grow * N + gcol] = f2bf(c);
                    else       ((float*)Cout)[(size_t)grow * N + gcol] = c;
                }
            }
        }
    }
}

// ---------------------------------------------------------------------------
// Point-wise attention, bf16 in/out, fp32 math, online softmax.
// ---------------------------------------------------------------------------
template<int NQ, int NS>
__global__ __launch_bounds__(256)
void pw_attn_bf16(const unsigned short* __restrict__ Q, const unsigned short* __restrict__ Kx,
                  const unsigned short* __restrict__ V, unsigned short* __restrict__ Out)
{
    const long long gid = (long long)blockIdx.x * 256 + threadIdx.x;
    const long long n = gid / NQ;
    const int l = (int)(gid % NQ);
    float qf[16];
    {
        const uint4* qp = (const uint4*)(Q + (size_t)n * NQ * 16 + (size_t)l * 16);
        bf8_to_f(qp[0], qf); bf8_to_f(qp[1], qf + 8);
    }
    const unsigned short* kp = Kx + (size_t)n * NS * 16;
    const unsigned short* vp = V  + (size_t)n * NS * 16;
    float m = -INFINITY, denom = 0.f;
    float acc[16] = {};
    for (int s = 0; s < NS; ++s) {
        float kf[16], vf[16];
        const uint4* kr = (const uint4*)(kp + s * 16);
        bf8_to_f(kr[0], kf); bf8_to_f(kr[1], kf + 8);
        float sc = 0.f;
        #pragma unroll
        for (int j = 0; j < 16; ++j) sc = fmaf(qf[j], kf[j], sc);
        sc *= 0.25f;
        const float nm = fmaxf(m, sc);
        const float fold = __expf(m - nm);
        const float es = __expf(sc - nm);
        denom = denom * fold + es;
        const uint4* vr = (const uint4*)(vp + s * 16);
        bf8_to_f(vr[0], vf); bf8_to_f(vr[1], vf + 8);
        #pragma unroll
        for (int j = 0; j < 16; ++j) acc[j] = acc[j] * fold + es * vf[j];
        m = nm;
    }
    const float inv = 1.f / denom;
    uint4 o0, o1;
    o0.x = packbf(acc[0] * inv,  acc[1] * inv);
    o0.y = packbf(acc[2] * inv,  acc[3] * inv);
    o0.z = packbf(acc[4] * inv,  acc[5] * inv);
    o0.w = packbf(acc[6] * inv,  acc[7] * inv);
    o1.x = packbf(acc[8] * inv,  acc[9] * inv);
    o1.y = packbf(acc[10] * inv, acc[11] * inv);
    o1.z = packbf(acc[12] * inv, acc[13] * inv);
    o1.w = packbf(acc[14] * inv, acc[15] * inv);
    uint4* op = (uint4*)(Out + (size_t)n * NQ * 16 + (size_t)l * 16);
    op[0] = o0; op[1] = o1;
}

// ---------------------------------------------------------------------------
// t = LayerNorm(elu(u)) * g + b ; bf16 in / bf16 out, fp32 math.
// ---------------------------------------------------------------------------
__global__ __launch_bounds__(256)
void elu_ln_bf16_kernel(const unsigned short* __restrict__ U, const float* __restrict__ g,
                        const float* __restrict__ bb, unsigned short* __restrict__ Out)
{
    const int row = blockIdx.x;
    const int t = threadIdx.x;
    const size_t base = (size_t)row * DFF + (size_t)t * 8;
    float vals[8];
    {
        const uint4 u4 = *(const uint4*)(U + base);
        bf8_to_f(u4, vals);
    }
    float s = 0.f, sq = 0.f;
    #pragma unroll
    for (int j = 0; j < 8; ++j) {
        const float e = vals[j] > 0.f ? vals[j] : expm1f(vals[j]);
        vals[j] = e;
        s += e; sq += e * e;
    }
    #pragma unroll
    for (int off = 32; off > 0; off >>= 1) {
        s  += __shfl_xor(s,  off, 64);
        sq += __shfl_xor(sq, off, 64);
    }
    __shared__ float rs[4], rq[4];
    const int wave = t >> 6, lane = t & 63;
    if (lane == 0) { rs[wave] = s; rq[wave] = sq; }
    __syncthreads();
    const float ts = rs[0] + rs[1] + rs[2] + rs[3];
    const float tq = rq[0] + rq[1] + rq[2] + rq[3];
    const float mean = ts * (1.f / 2048.f);
    const float var  = tq * (1.f / 2048.f) - mean * mean;
    const float rinv = rsqrtf(var + 1e-5f);
    const float4 g0 = *(const float4*)(g + t * 8);
    const float4 g1 = *(const float4*)(g + t * 8 + 4);
    const float4 b0 = *(const float4*)(bb + t * 8);
    const float4 b1 = *(const float4*)(bb + t * 8 + 4);
    float o[8];
    o[0] = (vals[0] - mean) * rinv * g0.x + b0.x;
    o[1] = (vals[1] - mean) * rinv * g0.y + b0.y;
    o[2] = (vals[2] - mean) * rinv * g0.z + b0.z;
    o[3] = (vals[3] - mean) * rinv * g0.w + b0.w;
    o[4] = (vals[4] - mean) * rinv * g1.x + b1.x;
    o[5] = (vals[5] - mean) * rinv * g1.y + b1.y;
    o[6] = (vals[6] - mean) * rinv * g1.z + b1.z;
    o[7] = (vals[7] - mean) * rinv * g1.w + b1.w;
    uint4 ov;
    ov.x = packbf(o[0], o[1]); ov.y = packbf(o[2], o[3]);
    ov.z = packbf(o[4], o[5]); ov.w = packbf(o[6], o[7]);
    *(uint4*)(Out + base) = ov;
}

// ---------------------------------------------------------------------------
extern "C" void kernel_launch(void* const* d_in, const int* in_sizes, int n_in,
                              void* d_out, int out_size, void* d_ws, size_t ws_size,
                              hipStream_t stream)
{
    const float* x        = (const float*)d_in[0];
    const float* attn_q_w = (const float*)d_in[1];
    const float* attn_q_b = (const float*)d_in[2];
    const float* attn_k_w = (const float*)d_in[3];
    const float* attn_k_b = (const float*)d_in[4];
    const float* attn_v_w = (const float*)d_in[5];
    const float* attn_v_b = (const float*)d_in[6];
    const float* attn_o_w = (const float*)d_in[7];
    const float* attn_o_b = (const float*)d_in[8];
    const float* enc_w    = (const float*)d_in[9];
    const float* enc_b    = (const float*)d_in[10];
    const float* ff1_q_w  = (const float*)d_in[11];
    const float* ff1_q_b  = (const float*)d_in[12];
    const float* ff1_k_w  = (const float*)d_in[13];
    const float* ff1_k_b  = (const float*)d_in[14];
    const float* ff1_v_w  = (const float*)d_in[15];
    const float* ff1_v_b  = (const float*)d_in[16];
    const float* ff1_o_w  = (const float*)d_in[17];
    const float* ff1_o_b  = (const float*)d_in[18];
    const float* ff2_q_w  = (const float*)d_in[19];
    const float* ff2_q_b  = (const float*)d_in[20];
    const float* ff2_k_w  = (const float*)d_in[21];
    const float* ff2_k_b  = (const float*)d_in[22];
    const float* ff2_v_w  = (const float*)d_in[23];
    const float* ff2_v_b  = (const float*)d_in[24];
    const float* ff2_o_w  = (const float*)d_in[25];
    const float* ff2_o_b  = (const float*)d_in[26];
    const float* ln_g     = (const float*)d_in[27];
    const float* ln_b     = (const float*)d_in[28];
    (void)in_sizes; (void)n_in; (void)out_size; (void)ws_size;

    float* yout = (float*)d_out;                      // [20544, 512] fp32
    float* Aout = yout + (size_t)N_ROWS * DD;         // [B,H,L,L] fp32

    // ---- workspace carve ----
    char* cur = (char*)d_ws;
    auto alloc = [&](size_t bytes) -> void* {
        void* p = (void*)cur;
        cur += (bytes + 255) & ~(size_t)255;
        return p;
    };
    const size_t F32S = (size_t)N_ROWS * DD * 4;      // fp32 [N,512]
    const size_t BFS  = (size_t)MP * DD * 2;          // bf16 [MP,512]
    const size_t BFG  = (size_t)MP * DFF * 2;         // bf16 [MP,2048]
    float* A1 = (float*)alloc(F32S);                  // q (frozen fp32)
    float* A2 = (float*)alloc(F32S);                  // k
    unsigned short* xbf = (unsigned short*)alloc(BFS);// x in bf16 [MP,512]
    unsigned short* S1 = (unsigned short*)alloc(BFS); // ctx -> z -> q2
    unsigned short* S2 = (unsigned short*)alloc(BFS); // ly -> k1 -> V2
    unsigned short* S3 = (unsigned short*)alloc(BFS); // v (bf16) -> v1
    unsigned short* G1 = (unsigned short*)alloc(BFG); // q1 -> t
    unsigned short* G2 = (unsigned short*)alloc(BFG); // V1 -> k2
    unsigned short* G3 = (unsigned short*)alloc(BFG); // u  -> v2
    unsigned short* wt_av  = (unsigned short*)alloc((size_t)DD * DD * 2);
    unsigned short* wt_ao  = (unsigned short*)alloc((size_t)DD * DD * 2);
    unsigned short* wt_enc = (unsigned short*)alloc((size_t)DD * DD * 2);
    unsigned short* wt_f1q = (unsigned short*)alloc((size_t)DFF * DD * 2);
    unsigned short* wt_f1k = (unsigned short*)alloc((size_t)DD * DD * 2);
    unsigned short* wt_f1v = (unsigned short*)alloc((size_t)DD * DD * 2);
    unsigned short* wt_f1o = (unsigned short*)alloc((size_t)DFF * DFF * 2);
    unsigned short* wt_f2q = (unsigned short*)alloc((size_t)DD * DFF * 2);
    unsigned short* wt_f2k = (unsigned short*)alloc((size_t)DFF * DFF * 2);
    unsigned short* wt_f2v = (unsigned short*)alloc((size_t)DFF * DFF * 2);
    unsigned short* wt_f2o = (unsigned short*)alloc((size_t)DD * DD * 2);

    const dim3 blk(256);
    const dim3 gq(161, DD / 64);                      // sgemm128: 161 x 8
    const dim3 gm512(MP / 128, DD / 128);             // 161 x 4
    const dim3 gm2048(MP / 128, DFF / 128);           // 161 x 16

    // ---- weight prep ----
    transpose_w_kernel<<<dim3(DD/32,  DD/32),  blk, 0, stream>>>(attn_v_w, wt_av,  DD,  DD);
    transpose_w_kernel<<<dim3(DD/32,  DD/32),  blk, 0, stream>>>(attn_o_w, wt_ao,  DD,  DD);
    transpose_w_kernel<<<dim3(DD/32,  DD/32),  blk, 0, stream>>>(enc_w,    wt_enc, DD,  DD);
    transpose_w_kernel<<<dim3(DFF/32, DD/32),  blk, 0, stream>>>(ff1_q_w,  wt_f1q, DD,  DFF);
    transpose_w_kernel<<<dim3(DD/32,  DD/32),  blk, 0, stream>>>(ff1_k_w,  wt_f1k, DD,  DD);
    transpose_w_kernel<<<dim3(DD/32,  DD/32),  blk, 0, stream>>>(ff1_v_w,  wt_f1v, DD,  DD);
    transpose_w_kernel<<<dim3(DFF/32, DFF/32), blk, 0, stream>>>(ff1_o_w,  wt_f1o, DFF, DFF);
    transpose_w_kernel<<<dim3(DD/32,  DFF/32), blk, 0, stream>>>(ff2_q_w,  wt_f2q, DFF, DD);
    transpose_w_kernel<<<dim3(DFF/32, DFF/32), blk, 0, stream>>>(ff2_k_w,  wt_f2k, DFF, DFF);
    transpose_w_kernel<<<dim3(DFF/32, DFF/32), blk, 0, stream>>>(ff2_v_w,  wt_f2v, DFF, DFF);
    transpose_w_kernel<<<dim3(DD/32,  DD/32),  blk, 0, stream>>>(ff2_o_w,  wt_f2o, DD,  DD);
    f32_to_bf16_kernel<<<dim3((MP * DD / 4 + 255) / 256), blk, 0, stream>>>(
        x, xbf, (long long)N_ROWS * DD, (long long)MP * DD);

    // ---- gattn: q,k frozen fp32; v via bf16 MFMA ----
    sgemm128_kernel<1><<<gq, blk, 0, stream>>>(x, attn_q_w, attn_q_b, A1, N_ROWS, DD, DD);   // q=relu
    sgemm128_kernel<0><<<gq, blk, 0, stream>>>(x, attn_k_w, attn_k_b, A2, N_ROWS, DD, DD);   // k
    mgemm_kernel<0,1,1><<<gm512, blk, 0, stream>>>(xbf, wt_av, attn_v_b, nullptr, S3, N_ROWS, DD, DD); // v=relu bf16
    scores64_kernel<<<dim3(6, 6, BB * HH), blk, 0, stream>>>(A1, A2, Aout);
    topk_softmax_kernel<<<dim3((BB * HH * LSEQ) / 4), blk, 0, stream>>>(Aout);
    av_bf16_kernel<<<dim3(11, BB * HH), blk, 0, stream>>>(Aout, S3, S1);                     // ctx bf16

    // ---- y path, all bf16 MFMA ----
    mgemm_kernel<1,2,1><<<gm512, blk, 0, stream>>>(S1, wt_ao, attn_o_b, x, S2, N_ROWS, DD, DD);     // ly = leaky(x+ctx@Wo+b)
    mgemm_kernel<0,0,1><<<gm512, blk, 0, stream>>>(S2, wt_enc, enc_b, nullptr, S1, N_ROWS, DD, DD); // z
    mgemm_kernel<0,1,1><<<gm2048, blk, 0, stream>>>(S1, wt_f1q, ff1_q_b, nullptr, G1, N_ROWS, DD, DFF); // q1
    mgemm_kernel<0,0,1><<<gm512, blk, 0, stream>>>(S1, wt_f1k, ff1_k_b, nullptr, S2, N_ROWS, DD, DD);   // k1
    mgemm_kernel<0,1,1><<<gm512, blk, 0, stream>>>(S1, wt_f1v, ff1_v_b, nullptr, S3, N_ROWS, DD, DD);   // v1
    pw_attn_bf16<128,32><<<dim3((N_ROWS * 128) / 256), blk, 0, stream>>>(G1, S2, S3, G2);               // V1
    mgemm_kernel<2,0,1><<<gm2048, blk, 0, stream>>>(G2, wt_f1o, ff1_o_b, G1, G3, N_ROWS, DFF, DFF);     // u = q1 + V1@Wo+b
    elu_ln_bf16_kernel<<<dim3(N_ROWS), blk, 0, stream>>>(G3, ln_g, ln_b, G1);                           // t
    mgemm_kernel<0,1,1><<<gm512, blk, 0, stream>>>(G1, wt_f2q, ff2_q_b, nullptr, S1, N_ROWS, DFF, DD);  // q2
    mgemm_kernel<0,0,1><<<gm2048, blk, 0, stream>>>(G1, wt_f2k, ff2_k_b, nullptr, G2, N_ROWS, DFF, DFF);// k2
    mgemm_kernel<0,1,1><<<gm2048, blk, 0, stream>>>(G1, wt_f2v, ff2_v_b, nullptr, G3, N_ROWS, DFF, DFF);// v2
    pw_attn_bf16<32,128><<<dim3((N_ROWS * 32) / 256), blk, 0, stream>>>(S1, G2, G3, S2);                // V2
    mgemm_kernel<2,0,0><<<gm512, blk, 0, stream>>>(S2, wt_f2o, ff2_o_b, S1, yout, N_ROWS, DD, DD);      // yout fp32
}

// Round 4
// 2810.932 us; speedup vs baseline: 3.9369x; 1.0977x over previous
//
#include <hip/hip_runtime.h>
#include <hip/hip_bf16.h>
#include <math.h>

// Problem constants (B=64, L=321, D=512, DFF=2048, H=8, E=64, P=16, TOPK=10)
#define N_ROWS 20544   // B*L
#define MP     20608   // padded to 161*128 for MFMA tiles
#define LSEQ   321
#define BB     64
#define HH     8
#define EE     64
#define DD     512
#define DFF    2048

typedef __attribute__((ext_vector_type(8))) short bf16x8;
typedef __attribute__((ext_vector_type(4))) float f32x4;

__device__ inline float bf2f(unsigned short v){ unsigned u = ((unsigned)v) << 16; return __builtin_bit_cast(float, u); }
__device__ inline unsigned short f2bf(float f){ __hip_bfloat16 h = __float2bfloat16(f); return __builtin_bit_cast(unsigned short, h); }
__device__ inline float lo16(unsigned u){ return __builtin_bit_cast(float, u << 16); }
__device__ inline float hi16(unsigned u){ return __builtin_bit_cast(float, u & 0xffff0000u); }
__device__ inline unsigned packbf(float a, float b){ return (unsigned)f2bf(a) | ((unsigned)f2bf(b) << 16); }
__device__ inline void bf8_to_f(uint4 u, float* o){
    o[0]=lo16(u.x); o[1]=hi16(u.x); o[2]=lo16(u.y); o[3]=hi16(u.y);
    o[4]=lo16(u.z); o[5]=hi16(u.z); o[6]=lo16(u.w); o[7]=hi16(u.w);
}

#define GLDS16(gp, lp) __builtin_amdgcn_global_load_lds( \
    (const __attribute__((address_space(1))) unsigned int*)(gp), \
    (__attribute__((address_space(3))) unsigned int*)(lp), 16, 0, 0)

// ---------------------------------------------------------------------------
// fp32 GEMM for q,k (feeds frozen scores->topk). FROZEN since round 3.
// ---------------------------------------------------------------------------
template<int POST>
__global__ __launch_bounds__(256)
void sgemm128_kernel(const float* __restrict__ A, const float* __restrict__ W,
                     const float* __restrict__ bias, float* __restrict__ C,
                     int M, int K, int N)
{
    __shared__ float As[16][132];   // [k][row], 128 rows + pad
    __shared__ float Bs[16][64];    // [k][col]
    const int t  = threadIdx.x;
    const int tx = t & 15, ty = t >> 4;
    const int row0 = blockIdx.x << 7, col0 = blockIdx.y << 6;
    const int ar = t >> 2;          // 0..63
    const int ak = (t & 3) << 2;    // 0,4,8,12
    const float* Wp = W + (size_t)ty * N + col0 + (tx << 2);
    float acc[8][4] = {};
    for (int k0 = 0; k0 < K; k0 += 16) {
        float4 a0 = make_float4(0.f,0.f,0.f,0.f);
        float4 a1 = make_float4(0.f,0.f,0.f,0.f);
        if (row0 + ar < M)      a0 = *(const float4*)(A + (size_t)(row0 + ar) * K + k0 + ak);
        if (row0 + ar + 64 < M) a1 = *(const float4*)(A + (size_t)(row0 + ar + 64) * K + k0 + ak);
        const float4 wv = *(const float4*)(Wp + (size_t)k0 * N);
        As[ak + 0][ar] = a0.x; As[ak + 1][ar] = a0.y;
        As[ak + 2][ar] = a0.z; As[ak + 3][ar] = a0.w;
        As[ak + 0][ar + 64] = a1.x; As[ak + 1][ar + 64] = a1.y;
        As[ak + 2][ar + 64] = a1.z; As[ak + 3][ar + 64] = a1.w;
        *(float4*)&Bs[ty][tx << 2] = wv;
        __syncthreads();
        #pragma unroll
        for (int kk = 0; kk < 16; ++kk) {
            const float4 aA = *(const float4*)&As[kk][ty << 3];
            const float4 aB = *(const float4*)&As[kk][(ty << 3) + 4];
            const float4 b4 = *(const float4*)&Bs[kk][tx << 2];
            const float a[8] = {aA.x, aA.y, aA.z, aA.w, aB.x, aB.y, aB.z, aB.w};
            const float b[4] = {b4.x, b4.y, b4.z, b4.w};
            #pragma unroll
            for (int i = 0; i < 8; ++i)
                #pragma unroll
                for (int j = 0; j < 4; ++j)
                    acc[i][j] = fmaf(a[i], b[j], acc[i][j]);
        }
        __syncthreads();
    }
    const float4 bi = *(const float4*)(bias + col0 + (tx << 2));
    #pragma unroll
    for (int i = 0; i < 8; ++i) {
        const int row = row0 + (ty << 3) + i;
        if (row < M) {
            float4 c;
            c.x = acc[i][0] + bi.x;
            c.y = acc[i][1] + bi.y;
            c.z = acc[i][2] + bi.z;
            c.w = acc[i][3] + bi.w;
            if (POST == 1) {
                c.x = fmaxf(c.x, 0.f); c.y = fmaxf(c.y, 0.f);
                c.z = fmaxf(c.z, 0.f); c.w = fmaxf(c.w, 0.f);
            }
            *(float4*)(C + (size_t)row * N + col0 + (tx << 2)) = c;
        }
    }
}

// ---------------------------------------------------------------------------
// FROZEN: scores 64x64 (round 3), same FP contraction as round 1.
// ---------------------------------------------------------------------------
__global__ __launch_bounds__(256)
void scores64_kernel(const float* __restrict__ Q, const float* __restrict__ Kx,
                     float* __restrict__ Sc)
{
    const int bh = blockIdx.z, b = bh >> 3, h = bh & 7;
    const int l0 = blockIdx.x << 6, s0 = blockIdx.y << 6;
    __shared__ float qs[64][68];
    __shared__ float ks[64][68];
    const int t = threadIdx.x;
    {
        const int r = t >> 4;           // 0..15
        const int c = (t & 15) << 2;    // 0..60
        #pragma unroll
        for (int i = 0; i < 4; ++i) {
            const int rr = r + (i << 4);
            const int l = l0 + rr, s = s0 + rr;
            float4 qv = make_float4(0.f, 0.f, 0.f, 0.f);
            float4 kv = make_float4(0.f, 0.f, 0.f, 0.f);
            if (l < LSEQ) qv = *(const float4*)(Q + ((size_t)(b * LSEQ + l)) * DD + h * EE + c);
            if (s < LSEQ) kv = *(const float4*)(Kx + ((size_t)(b * LSEQ + s)) * DD + h * EE + c);
            *(float4*)&qs[rr][c] = qv;
            *(float4*)&ks[rr][c] = kv;
        }
    }
    __syncthreads();
    const int tx = t & 15, ty = t >> 4;
    float acc[4][4] = {};
    for (int e = 0; e < EE; e += 4) {
        float4 q4[4], k4[4];
        #pragma unroll
        for (int i = 0; i < 4; ++i) q4[i] = *(const float4*)&qs[ty + (i << 4)][e];
        #pragma unroll
        for (int j = 0; j < 4; ++j) k4[j] = *(const float4*)&ks[tx + (j << 4)][e];
        #pragma unroll
        for (int i = 0; i < 4; ++i)
            #pragma unroll
            for (int j = 0; j < 4; ++j)
                acc[i][j] += q4[i].x * k4[j].x + q4[i].y * k4[j].y + q4[i].z * k4[j].z + q4[i].w * k4[j].w;
    }
    #pragma unroll
    for (int i = 0; i < 4; ++i) {
        const int l = l0 + ty + (i << 4);
        if (l < LSEQ) {
            #pragma unroll
            for (int j = 0; j < 4; ++j) {
                const int s = s0 + tx + (j << 4);
                if (s < LSEQ)
                    Sc[((size_t)bh * LSEQ + l) * LSEQ + s] = acc[i][j];
            }
        }
    }
}

// ---------------------------------------------------------------------------
// FROZEN: topk/softmax (bit-identical to round 1)
// ---------------------------------------------------------------------------
__global__ __launch_bounds__(256)
void topk_softmax_kernel(float* __restrict__ S)
{
    const int wave = threadIdx.x >> 6;
    const int lane = threadIdx.x & 63;
    const size_t row = (size_t)blockIdx.x * 4 + wave;
    float* p = S + row * LSEQ;
    float v[6], w[6];
    #pragma unroll
    for (int j = 0; j < 6; ++j) {
        const int idx = lane + (j << 6);
        v[j] = (idx < LSEQ) ? p[idx] : -INFINITY;
        w[j] = v[j];
    }
    float gmax = 0.f, kth = 0.f;
    #pragma unroll
    for (int it = 0; it < 10; ++it) {
        float m = w[0];
        #pragma unroll
        for (int j = 1; j < 6; ++j) m = fmaxf(m, w[j]);
        #pragma unroll
        for (int off = 32; off > 0; off >>= 1)
            m = fmaxf(m, __shfl_xor(m, off, 64));
        if (it == 0) gmax = m;
        kth = m;
        if (it < 9) {
            int which = -1;
            #pragma unroll
            for (int j = 0; j < 6; ++j)
                if (which < 0 && w[j] == m) which = j;
            const unsigned long long msk = __ballot(which >= 0);
            const int first = __ffsll(msk) - 1;
            if (lane == first) {
                #pragma unroll
                for (int j = 0; j < 6; ++j)
                    if (j == which) w[j] = -INFINITY;
            }
        }
    }
    float ssum = 0.f;
    float e[6];
    #pragma unroll
    for (int j = 0; j < 6; ++j) {
        e[j] = (v[j] >= kth) ? __expf(0.125f * (v[j] - gmax)) : 0.f;
        ssum += e[j];
    }
    #pragma unroll
    for (int off = 32; off > 0; off >>= 1) ssum += __shfl_xor(ssum, off, 64);
    const float inv = 1.f / ssum;
    #pragma unroll
    for (int j = 0; j < 6; ++j) {
        const int idx = lane + (j << 6);
        if (idx < LSEQ) p[idx] = e[j] * inv;
    }
}

// ---------------------------------------------------------------------------
// A@V: A fp32 (softmax weights), V bf16; ctx out bf16. FROZEN (round 3).
// ---------------------------------------------------------------------------
__global__ __launch_bounds__(256)
void av_bf16_kernel(const float* __restrict__ A, const unsigned short* __restrict__ V,
                    unsigned short* __restrict__ Out)
{
    const int bh = blockIdx.y, b = bh >> 3, h = bh & 7;
    const int l0 = blockIdx.x << 5;
    __shared__ float As[32][36];
    __shared__ float Vs[32][68];
    const int t = threadIdx.x;
    const int tx = t & 15, ty = t >> 4;
    float acc[2][4] = {};
    for (int s0 = 0; s0 < LSEQ; s0 += 32) {
        {
            const int r = t >> 3, c = (t & 7) << 2;
            const int l = l0 + r;
            const float* ap = A + ((size_t)bh * LSEQ + (l < LSEQ ? l : 0)) * LSEQ + s0 + c;
            #pragma unroll
            for (int jj = 0; jj < 4; ++jj) {
                const int s = s0 + c + jj;
                As[r][c + jj] = (l < LSEQ && s < LSEQ) ? ap[jj] : 0.f;
            }
        }
        #pragma unroll
        for (int pass = 0; pass < 2; ++pass) {
            const int r = (t >> 4) + (pass << 4), c = (t & 15) << 2;
            const int s = s0 + r;
            float4 vv = make_float4(0.f, 0.f, 0.f, 0.f);
            if (s < LSEQ) {
                const ushort4 u = *(const ushort4*)(V + ((size_t)(b * LSEQ + s)) * DD + h * EE + c);
                vv.x = bf2f(u.x); vv.y = bf2f(u.y); vv.z = bf2f(u.z); vv.w = bf2f(u.w);
            }
            *(float4*)&Vs[r][c] = vv;
        }
        __syncthreads();
        #pragma unroll
        for (int ss = 0; ss < 32; ++ss) {
            const float a0 = As[(ty << 1) + 0][ss];
            const float a1 = As[(ty << 1) + 1][ss];
            const float4 vv = *(const float4*)&Vs[ss][tx << 2];
            acc[0][0] = fmaf(a0, vv.x, acc[0][0]);
            acc[0][1] = fmaf(a0, vv.y, acc[0][1]);
            acc[0][2] = fmaf(a0, vv.z, acc[0][2]);
            acc[0][3] = fmaf(a0, vv.w, acc[0][3]);
            acc[1][0] = fmaf(a1, vv.x, acc[1][0]);
            acc[1][1] = fmaf(a1, vv.y, acc[1][1]);
            acc[1][2] = fmaf(a1, vv.z, acc[1][2]);
            acc[1][3] = fmaf(a1, vv.w, acc[1][3]);
        }
        __syncthreads();
    }
    #pragma unroll
    for (int i = 0; i < 2; ++i) {
        const int l = l0 + (ty << 1) + i;
        if (l < LSEQ) {
            ushort4 o;
            o.x = f2bf(acc[i][0]); o.y = f2bf(acc[i][1]);
            o.z = f2bf(acc[i][2]); o.w = f2bf(acc[i][3]);
            *(ushort4*)(Out + ((size_t)(b * LSEQ + l)) * DD + h * EE + (tx << 2)) = o;
        }
    }
}

// ---------------------------------------------------------------------------
// fp32 -> bf16 convert (x staging for MFMA); pads tail rows with zeros.
// ---------------------------------------------------------------------------
__global__ __launch_bounds__(256)
void f32_to_bf16_kernel(const float* __restrict__ X, unsigned short* __restrict__ Y,
                        long long nvalid, long long ntotal)
{
    const long long i = ((long long)blockIdx.x * 256 + threadIdx.x) * 4;
    if (i >= ntotal) return;
    float4 v = make_float4(0.f, 0.f, 0.f, 0.f);
    if (i < nvalid) v = *(const float4*)(X + i);
    ushort4 o;
    o.x = f2bf(v.x); o.y = f2bf(v.y); o.z = f2bf(v.z); o.w = f2bf(v.w);
    *(ushort4*)(Y + i) = o;
}

// ---------------------------------------------------------------------------
// Weight prep: fp32 W[K][N] -> bf16 W^T[N][K]
// ---------------------------------------------------------------------------
__global__ __launch_bounds__(256)
void transpose_w_kernel(const float* __restrict__ W, unsigned short* __restrict__ Wt,
                        int K, int N)
{
    __shared__ unsigned short s[32][33];
    const int n0 = blockIdx.x << 5, k0 = blockIdx.y << 5;
    const int tx = threadIdx.x & 31, ty = threadIdx.x >> 5;
    #pragma unroll
    for (int i = 0; i < 32; i += 8)
        s[ty + i][tx] = f2bf(W[(size_t)(k0 + ty + i) * N + n0 + tx]);
    __syncthreads();
    #pragma unroll
    for (int i = 0; i < 32; i += 8)
        Wt[(size_t)(n0 + ty + i) * K + k0 + tx] = s[tx][ty + i];
}

// ---------------------------------------------------------------------------
// bf16 MFMA GEMM. Round 4 changes:
//  (a) grid transposed: blockIdx.x = COL tile, blockIdx.y = ROW tile, so
//      consecutive blocks share the A row-tile (L2/LLC reuse, kills the
//      11x A over-fetch seen in round 3's FETCH_SIZE).
//  (b) XOR-swizzled LDS: global 16B-chunk c^((r>>1)&3) stored at LDS chunk c
//      (swizzle applied on the GLOBAL address side — legal under the
//      wave-uniform global_load_lds constraint, same cache lines).
//      Fragment ds_read_b128 offsets apply the matching swizzle ->
//      max 2-way bank aliasing (free) instead of 8-way.
// ---------------------------------------------------------------------------
template<int RES, int POST, int OUTBF>
__global__ __launch_bounds__(256)
void mgemm_kernel(const unsigned short* __restrict__ A, const unsigned short* __restrict__ Bt,
                  const float* __restrict__ bias, const void* __restrict__ Rres,
                  void* __restrict__ Cout, int M, int K, int N)
{
    __shared__ unsigned short As[128 * 32];
    __shared__ unsigned short Bs[128 * 32];
    const int t = threadIdx.x;
    const int lane = t & 63;
    const int wave = t >> 6;
    const int row0 = blockIdx.y << 7, col0 = blockIdx.x << 7;   // (a) transposed
    const int wm = (wave >> 1) << 6, wn = (wave & 1) << 6;
    // staging: thread t = row t>>2, LDS chunk t&3; loads global chunk (t&3)^((t>>3)&3)
    const int r0 = t >> 2;
    const int kh = ((t & 3) ^ ((t >> 3) & 3)) << 3;             // (b) swizzle
    const unsigned short* Ag0 = A + (size_t)(row0 + r0) * K + kh;
    const unsigned short* Ag1 = Ag0 + (size_t)64 * K;
    const unsigned short* Bg0 = Bt + (size_t)(col0 + r0) * K + kh;
    const unsigned short* Bg1 = Bg0 + (size_t)64 * K;
    unsigned short* As0 = As + t * 8;  unsigned short* As1 = As0 + 2048;
    unsigned short* Bs0 = Bs + t * 8;  unsigned short* Bs1 = Bs0 + 2048;
    // fragment read offsets (swizzle-matched), k0-invariant
    const int fm = lane & 15, q = lane >> 4;
    int aoff[4], boff[4];
    #pragma unroll
    for (int i = 0; i < 4; ++i) {
        const int Ra = wm + (i << 4) + fm;
        aoff[i] = Ra * 32 + ((q ^ ((Ra >> 1) & 3)) << 3);
        const int Rb = wn + (i << 4) + fm;
        boff[i] = Rb * 32 + ((q ^ ((Rb >> 1) & 3)) << 3);
    }
    f32x4 acc[4][4] = {};
    for (int k0 = 0; k0 < K; k0 += 32) {
        GLDS16(Ag0 + k0, As0);
        GLDS16(Ag1 + k0, As1);
        GLDS16(Bg0 + k0, Bs0);
        GLDS16(Bg1 + k0, Bs1);
        __syncthreads();
        bf16x8 af[4], bfr[4];
        #pragma unroll
        for (int i = 0; i < 4; ++i) {
            af[i]  = *(const bf16x8*)(As + aoff[i]);
            bfr[i] = *(const bf16x8*)(Bs + boff[i]);
        }
        #pragma unroll
        for (int i = 0; i < 4; ++i)
            #pragma unroll
            for (int j = 0; j < 4; ++j)
                acc[i][j] = __builtin_amdgcn_mfma_f32_16x16x32_bf16(af[i], bfr[j], acc[i][j], 0, 0, 0);
        __syncthreads();
    }
    const int qr = (lane >> 4) << 2;
    #pragma unroll
    for (int j = 0; j < 4; ++j) {
        const int gcol = col0 + wn + (j << 4) + fm;
        const float bj = bias[gcol];
        #pragma unroll
        for (int i = 0; i < 4; ++i) {
            const int rb = row0 + wm + (i << 4) + qr;
            #pragma unroll
            for (int rg = 0; rg < 4; ++rg) {
                const int grow = rb + rg;
                if (grow < M) {
                    float c = acc[i][j][rg] + bj;
                    if (RES == 1) c += ((const float*)Rres)[(size_t)grow * N + gcol];
                    if (RES == 2) c += bf2f(((const unsigned short*)Rres)[(size_t)grow * N + gcol]);
                    if (POST == 1) c = fmaxf(c, 0.f);
                    if (POST == 2) c = c >= 0.f ? c : 0.5f * c;
                    if (OUTBF) ((unsigned short*)Cout)[(size_t)grow * N + gcol] = f2bf(c);
                    else       ((float*)Cout)[(size_t)grow * N + gcol] = c;
                }
            }
        }
    }
}

// ---------------------------------------------------------------------------
// Point-wise attention, bf16 in/out, fp32 math, online softmax.
// ---------------------------------------------------------------------------
template<int NQ, int NS>
__global__ __launch_bounds__(256)
void pw_attn_bf16(const unsigned short* __restrict__ Q, const unsigned short* __restrict__ Kx,
                  const unsigned short* __restrict__ V, unsigned short* __restrict__ Out)
{
    const long long gid = (long long)blockIdx.x * 256 + threadIdx.x;
    const long long n = gid / NQ;
    const int l = (int)(gid % NQ);
    float qf[16];
    {
        const uint4* qp = (const uint4*)(Q + (size_t)n * NQ * 16 + (size_t)l * 16);
        bf8_to_f(qp[0], qf); bf8_to_f(qp[1], qf + 8);
    }
    const unsigned short* kp = Kx + (size_t)n * NS * 16;
    const unsigned short* vp = V  + (size_t)n * NS * 16;
    float m = -INFINITY, denom = 0.f;
    float acc[16] = {};
    for (int s = 0; s < NS; ++s) {
        float kf[16], vf[16];
        const uint4* kr = (const uint4*)(kp + s * 16);
        bf8_to_f(kr[0], kf); bf8_to_f(kr[1], kf + 8);
        float sc = 0.f;
        #pragma unroll
        for (int j = 0; j < 16; ++j) sc = fmaf(qf[j], kf[j], sc);
        sc *= 0.25f;
        const float nm = fmaxf(m, sc);
        const float fold = __expf(m - nm);
        const float es = __expf(sc - nm);
        denom = denom * fold + es;
        const uint4* vr = (const uint4*)(vp + s * 16);
        bf8_to_f(vr[0], vf); bf8_to_f(vr[1], vf + 8);
        #pragma unroll
        for (int j = 0; j < 16; ++j) acc[j] = acc[j] * fold + es * vf[j];
        m = nm;
    }
    const float inv = 1.f / denom;
    uint4 o0, o1;
    o0.x = packbf(acc[0] * inv,  acc[1] * inv);
    o0.y = packbf(acc[2] * inv,  acc[3] * inv);
    o0.z = packbf(acc[4] * inv,  acc[5] * inv);
    o0.w = packbf(acc[6] * inv,  acc[7] * inv);
    o1.x = packbf(acc[8] * inv,  acc[9] * inv);
    o1.y = packbf(acc[10] * inv, acc[11] * inv);
    o1.z = packbf(acc[12] * inv, acc[13] * inv);
    o1.w = packbf(acc[14] * inv, acc[15] * inv);
    uint4* op = (uint4*)(Out + (size_t)n * NQ * 16 + (size_t)l * 16);
    op[0] = o0; op[1] = o1;
}

// ---------------------------------------------------------------------------
// t = LayerNorm(elu(u)) * g + b ; bf16 in / bf16 out, fp32 math.
// ---------------------------------------------------------------------------
__global__ __launch_bounds__(256)
void elu_ln_bf16_kernel(const unsigned short* __restrict__ U, const float* __restrict__ g,
                        const float* __restrict__ bb, unsigned short* __restrict__ Out)
{
    const int row = blockIdx.x;
    const int t = threadIdx.x;
    const size_t base = (size_t)row * DFF + (size_t)t * 8;
    float vals[8];
    {
        const uint4 u4 = *(const uint4*)(U + base);
        bf8_to_f(u4, vals);
    }
    float s = 0.f, sq = 0.f;
    #pragma unroll
    for (int j = 0; j < 8; ++j) {
        const float e = vals[j] > 0.f ? vals[j] : expm1f(vals[j]);
        vals[j] = e;
        s += e; sq += e * e;
    }
    #pragma unroll
    for (int off = 32; off > 0; off >>= 1) {
        s  += __shfl_xor(s,  off, 64);
        sq += __shfl_xor(sq, off, 64);
    }
    __shared__ float rs[4], rq[4];
    const int wave = t >> 6, lane = t & 63;
    if (lane == 0) { rs[wave] = s; rq[wave] = sq; }
    __syncthreads();
    const float ts = rs[0] + rs[1] + rs[2] + rs[3];
    const float tq = rq[0] + rq[1] + rq[2] + rq[3];
    const float mean = ts * (1.f / 2048.f);
    const float var  = tq * (1.f / 2048.f) - mean * mean;
    const float rinv = rsqrtf(var + 1e-5f);
    const float4 g0 = *(const float4*)(g + t * 8);
    const float4 g1 = *(const float4*)(g + t * 8 + 4);
    const float4 b0 = *(const float4*)(bb + t * 8);
    const float4 b1 = *(const float4*)(bb + t * 8 + 4);
    float o[8];
    o[0] = (vals[0] - mean) * rinv * g0.x + b0.x;
    o[1] = (vals[1] - mean) * rinv * g0.y + b0.y;
    o[2] = (vals[2] - mean) * rinv * g0.z + b0.z;
    o[3] = (vals[3] - mean) * rinv * g0.w + b0.w;
    o[4] = (vals[4] - mean) * rinv * g1.x + b1.x;
    o[5] = (vals[5] - mean) * rinv * g1.y + b1.y;
    o[6] = (vals[6] - mean) * rinv * g1.z + b1.z;
    o[7] = (vals[7] - mean) * rinv * g1.w + b1.w;
    uint4 ov;
    ov.x = packbf(o[0], o[1]); ov.y = packbf(o[2], o[3]);
    ov.z = packbf(o[4], o[5]); ov.w = packbf(o[6], o[7]);
    *(uint4*)(Out + base) = ov;
}

// ---------------------------------------------------------------------------
extern "C" void kernel_launch(void* const* d_in, const int* in_sizes, int n_in,
                              void* d_out, int out_size, void* d_ws, size_t ws_size,
                              hipStream_t stream)
{
    const float* x        = (const float*)d_in[0];
    const float* attn_q_w = (const float*)d_in[1];
    const float* attn_q_b = (const float*)d_in[2];
    const float* attn_k_w = (const float*)d_in[3];
    const float* attn_k_b = (const float*)d_in[4];
    const float* attn_v_w = (const float*)d_in[5];
    const float* attn_v_b = (const float*)d_in[6];
    const float* attn_o_w = (const float*)d_in[7];
    const float* attn_o_b = (const float*)d_in[8];
    const float* enc_w    = (const float*)d_in[9];
    const float* enc_b    = (const float*)d_in[10];
    const float* ff1_q_w  = (const float*)d_in[11];
    const float* ff1_q_b  = (const float*)d_in[12];
    const float* ff1_k_w  = (const float*)d_in[13];
    const float* ff1_k_b  = (const float*)d_in[14];
    const float* ff1_v_w  = (const float*)d_in[15];
    const float* ff1_v_b  = (const float*)d_in[16];
    const float* ff1_o_w  = (const float*)d_in[17];
    const float* ff1_o_b  = (const float*)d_in[18];
    const float* ff2_q_w  = (const float*)d_in[19];
    const float* ff2_q_b  = (const float*)d_in[20];
    const float* ff2_k_w  = (const float*)d_in[21];
    const float* ff2_k_b  = (const float*)d_in[22];
    const float* ff2_v_w  = (const float*)d_in[23];
    const float* ff2_v_b  = (const float*)d_in[24];
    const float* ff2_o_w  = (const float*)d_in[25];
    const float* ff2_o_b  = (const float*)d_in[26];
    const float* ln_g     = (const float*)d_in[27];
    const float* ln_b     = (const float*)d_in[28];
    (void)in_sizes; (void)n_in; (void)out_size; (void)ws_size;

    float* yout = (float*)d_out;                      // [20544, 512] fp32
    float* Aout = yout + (size_t)N_ROWS * DD;         // [B,H,L,L] fp32

    // ---- workspace carve ----
    char* cur = (char*)d_ws;
    auto alloc = [&](size_t bytes) -> void* {
        void* p = (void*)cur;
        cur += (bytes + 255) & ~(size_t)255;
        return p;
    };
    const size_t F32S = (size_t)N_ROWS * DD * 4;      // fp32 [N,512]
    const size_t BFS  = (size_t)MP * DD * 2;          // bf16 [MP,512]
    const size_t BFG  = (size_t)MP * DFF * 2;         // bf16 [MP,2048]
    float* A1 = (float*)alloc(F32S);                  // q (frozen fp32)
    float* A2 = (float*)alloc(F32S);                  // k
    unsigned short* xbf = (unsigned short*)alloc(BFS);// x in bf16 [MP,512]
    unsigned short* S1 = (unsigned short*)alloc(BFS); // ctx -> z -> q2
    unsigned short* S2 = (unsigned short*)alloc(BFS); // ly -> k1 -> V2
    unsigned short* S3 = (unsigned short*)alloc(BFS); // v (bf16) -> v1
    unsigned short* G1 = (unsigned short*)alloc(BFG); // q1 -> t
    unsigned short* G2 = (unsigned short*)alloc(BFG); // V1 -> k2
    unsigned short* G3 = (unsigned short*)alloc(BFG); // u  -> v2
    unsigned short* wt_av  = (unsigned short*)alloc((size_t)DD * DD * 2);
    unsigned short* wt_ao  = (unsigned short*)alloc((size_t)DD * DD * 2);
    unsigned short* wt_enc = (unsigned short*)alloc((size_t)DD * DD * 2);
    unsigned short* wt_f1q = (unsigned short*)alloc((size_t)DFF * DD * 2);
    unsigned short* wt_f1k = (unsigned short*)alloc((size_t)DD * DD * 2);
    unsigned short* wt_f1v = (unsigned short*)alloc((size_t)DD * DD * 2);
    unsigned short* wt_f1o = (unsigned short*)alloc((size_t)DFF * DFF * 2);
    unsigned short* wt_f2q = (unsigned short*)alloc((size_t)DD * DFF * 2);
    unsigned short* wt_f2k = (unsigned short*)alloc((size_t)DFF * DFF * 2);
    unsigned short* wt_f2v = (unsigned short*)alloc((size_t)DFF * DFF * 2);
    unsigned short* wt_f2o = (unsigned short*)alloc((size_t)DD * DD * 2);

    const dim3 blk(256);
    const dim3 gq(161, DD / 64);                      // sgemm128: 161 x 8
    const dim3 gm512(DD / 128, MP / 128);             // (col, row) = 4 x 161
    const dim3 gm2048(DFF / 128, MP / 128);           // (col, row) = 16 x 161

    // ---- weight prep ----
    transpose_w_kernel<<<dim3(DD/32,  DD/32),  blk, 0, stream>>>(attn_v_w, wt_av,  DD,  DD);
    transpose_w_kernel<<<dim3(DD/32,  DD/32),  blk, 0, stream>>>(attn_o_w, wt_ao,  DD,  DD);
    transpose_w_kernel<<<dim3(DD/32,  DD/32),  blk, 0, stream>>>(enc_w,    wt_enc, DD,  DD);
    transpose_w_kernel<<<dim3(DFF/32, DD/32),  blk, 0, stream>>>(ff1_q_w,  wt_f1q, DD,  DFF);
    transpose_w_kernel<<<dim3(DD/32,  DD/32),  blk, 0, stream>>>(ff1_k_w,  wt_f1k, DD,  DD);
    transpose_w_kernel<<<dim3(DD/32,  DD/32),  blk, 0, stream>>>(ff1_v_w,  wt_f1v, DD,  DD);
    transpose_w_kernel<<<dim3(DFF/32, DFF/32), blk, 0, stream>>>(ff1_o_w,  wt_f1o, DFF, DFF);
    transpose_w_kernel<<<dim3(DD/32,  DFF/32), blk, 0, stream>>>(ff2_q_w,  wt_f2q, DFF, DD);
    transpose_w_kernel<<<dim3(DFF/32, DFF/32), blk, 0, stream>>>(ff2_k_w,  wt_f2k, DFF, DFF);
    transpose_w_kernel<<<dim3(DFF/32, DFF/32), blk, 0, stream>>>(ff2_v_w,  wt_f2v, DFF, DFF);
    transpose_w_kernel<<<dim3(DD/32,  DD/32),  blk, 0, stream>>>(ff2_o_w,  wt_f2o, DD,  DD);
    f32_to_bf16_kernel<<<dim3((MP * DD / 4 + 255) / 256), blk, 0, stream>>>(
        x, xbf, (long long)N_ROWS * DD, (long long)MP * DD);

    // ---- gattn: q,k frozen fp32; v via bf16 MFMA ----
    sgemm128_kernel<1><<<gq, blk, 0, stream>>>(x, attn_q_w, attn_q_b, A1, N_ROWS, DD, DD);   // q=relu
    sgemm128_kernel<0><<<gq, blk, 0, stream>>>(x, attn_k_w, attn_k_b, A2, N_ROWS, DD, DD);   // k
    mgemm_kernel<0,1,1><<<gm512, blk, 0, stream>>>(xbf, wt_av, attn_v_b, nullptr, S3, N_ROWS, DD, DD); // v=relu bf16
    scores64_kernel<<<dim3(6, 6, BB * HH), blk, 0, stream>>>(A1, A2, Aout);
    topk_softmax_kernel<<<dim3((BB * HH * LSEQ) / 4), blk, 0, stream>>>(Aout);
    av_bf16_kernel<<<dim3(11, BB * HH), blk, 0, stream>>>(Aout, S3, S1);                     // ctx bf16

    // ---- y path, all bf16 MFMA ----
    mgemm_kernel<1,2,1><<<gm512, blk, 0, stream>>>(S1, wt_ao, attn_o_b, x, S2, N_ROWS, DD, DD);     // ly = leaky(x+ctx@Wo+b)
    mgemm_kernel<0,0,1><<<gm512, blk, 0, stream>>>(S2, wt_enc, enc_b, nullptr, S1, N_ROWS, DD, DD); // z
    mgemm_kernel<0,1,1><<<gm2048, blk, 0, stream>>>(S1, wt_f1q, ff1_q_b, nullptr, G1, N_ROWS, DD, DFF); // q1
    mgemm_kernel<0,0,1><<<gm512, blk, 0, stream>>>(S1, wt_f1k, ff1_k_b, nullptr, S2, N_ROWS, DD, DD);   // k1
    mgemm_kernel<0,1,1><<<gm512, blk, 0, stream>>>(S1, wt_f1v, ff1_v_b, nullptr, S3, N_ROWS, DD, DD);   // v1
    pw_attn_bf16<128,32><<<dim3((N_ROWS * 128) / 256), blk, 0, stream>>>(G1, S2, S3, G2);               // V1
    mgemm_kernel<2,0,1><<<gm2048, blk, 0, stream>>>(G2, wt_f1o, ff1_o_b, G1, G3, N_ROWS, DFF, DFF);     // u = q1 + V1@Wo+b
    elu_ln_bf16_kernel<<<dim3(N_ROWS), blk, 0, stream>>>(G3, ln_g, ln_b, G1);                           // t
    mgemm_kernel<0,1,1><<<gm512, blk, 0, stream>>>(G1, wt_f2q, ff2_q_b, nullptr, S1, N_ROWS, DFF, DD);  // q2
    mgemm_kernel<0,0,1><<<gm2048, blk, 0, stream>>>(G1, wt_f2k, ff2_k_b, nullptr, G2, N_ROWS, DFF, DFF);// k2
    mgemm_kernel<0,1,1><<<gm2048, blk, 0, stream>>>(G1, wt_f2v, ff2_v_b, nullptr, G3, N_ROWS, DFF, DFF);// v2
    pw_attn_bf16<32,128><<<dim3((N_ROWS * 32) / 256), blk, 0, stream>>>(S1, G2, G3, S2);                // V2
    mgemm_kernel<2,0,0><<<gm512, blk, 0, stream>>>(S2, wt_f2o, ff2_o_b, S1, yout, N_ROWS, DD, DD);      // yout fp32
}

// Round 5
// 2779.656 us; speedup vs baseline: 3.9812x; 1.0113x over previous
//
#include <hip/hip_runtime.h>
#include <hip/hip_bf16.h>
#include <math.h>

// Problem constants (B=64, L=321, D=512, DFF=2048, H=8, E=64, P=16, TOPK=10)
#define N_ROWS 20544   // B*L
#define MP     20608   // padded to 161*128 for MFMA tiles
#define LSEQ   321
#define BB     64
#define HH     8
#define EE     64
#define DD     512
#define DFF    2048

typedef __attribute__((ext_vector_type(8))) short bf16x8;
typedef __attribute__((ext_vector_type(4))) float f32x4;

__device__ inline float bf2f(unsigned short v){ unsigned u = ((unsigned)v) << 16; return __builtin_bit_cast(float, u); }
__device__ inline unsigned short f2bf(float f){ __hip_bfloat16 h = __float2bfloat16(f); return __builtin_bit_cast(unsigned short, h); }
__device__ inline float lo16(unsigned u){ return __builtin_bit_cast(float, u << 16); }
__device__ inline float hi16(unsigned u){ return __builtin_bit_cast(float, u & 0xffff0000u); }
__device__ inline unsigned packbf(float a, float b){ return (unsigned)f2bf(a) | ((unsigned)f2bf(b) << 16); }
__device__ inline void bf8_to_f(uint4 u, float* o){
    o[0]=lo16(u.x); o[1]=hi16(u.x); o[2]=lo16(u.y); o[3]=hi16(u.y);
    o[4]=lo16(u.z); o[5]=hi16(u.z); o[6]=lo16(u.w); o[7]=hi16(u.w);
}

#define GLDS16(gp, lp) __builtin_amdgcn_global_load_lds( \
    (const __attribute__((address_space(1))) unsigned int*)(gp), \
    (__attribute__((address_space(3))) unsigned int*)(lp), 16, 0, 0)

// XCD-aware remap: dispatch id n lands on XCD n%8 (heuristic). Give each XCD
// a contiguous block range, col-fastest, so one A row-strip stays in ONE
// XCD's L2 instead of being fetched by all eight.
__device__ inline void xcd_remap(int lin, int total, int ncols, int& row0, int& col0)
{
    const int per = total >> 3, rem = total & 7;
    const int xcd = lin & 7, i = lin >> 3;
    const int g = xcd * per + (xcd < rem ? xcd : rem) + i;
    row0 = (g / ncols) << 7;
    col0 = (g % ncols) << 7;
}

// ---------------------------------------------------------------------------
// fp32 GEMM for q,k (feeds frozen scores->topk). FROZEN since round 3.
// ---------------------------------------------------------------------------
template<int POST>
__global__ __launch_bounds__(256)
void sgemm128_kernel(const float* __restrict__ A, const float* __restrict__ W,
                     const float* __restrict__ bias, float* __restrict__ C,
                     int M, int K, int N)
{
    __shared__ float As[16][132];
    __shared__ float Bs[16][64];
    const int t  = threadIdx.x;
    const int tx = t & 15, ty = t >> 4;
    const int row0 = blockIdx.x << 7, col0 = blockIdx.y << 6;
    const int ar = t >> 2;
    const int ak = (t & 3) << 2;
    const float* Wp = W + (size_t)ty * N + col0 + (tx << 2);
    float acc[8][4] = {};
    for (int k0 = 0; k0 < K; k0 += 16) {
        float4 a0 = make_float4(0.f,0.f,0.f,0.f);
        float4 a1 = make_float4(0.f,0.f,0.f,0.f);
        if (row0 + ar < M)      a0 = *(const float4*)(A + (size_t)(row0 + ar) * K + k0 + ak);
        if (row0 + ar + 64 < M) a1 = *(const float4*)(A + (size_t)(row0 + ar + 64) * K + k0 + ak);
        const float4 wv = *(const float4*)(Wp + (size_t)k0 * N);
        As[ak + 0][ar] = a0.x; As[ak + 1][ar] = a0.y;
        As[ak + 2][ar] = a0.z; As[ak + 3][ar] = a0.w;
        As[ak + 0][ar + 64] = a1.x; As[ak + 1][ar + 64] = a1.y;
        As[ak + 2][ar + 64] = a1.z; As[ak + 3][ar + 64] = a1.w;
        *(float4*)&Bs[ty][tx << 2] = wv;
        __syncthreads();
        #pragma unroll
        for (int kk = 0; kk < 16; ++kk) {
            const float4 aA = *(const float4*)&As[kk][ty << 3];
            const float4 aB = *(const float4*)&As[kk][(ty << 3) + 4];
            const float4 b4 = *(const float4*)&Bs[kk][tx << 2];
            const float a[8] = {aA.x, aA.y, aA.z, aA.w, aB.x, aB.y, aB.z, aB.w};
            const float b[4] = {b4.x, b4.y, b4.z, b4.w};
            #pragma unroll
            for (int i = 0; i < 8; ++i)
                #pragma unroll
                for (int j = 0; j < 4; ++j)
                    acc[i][j] = fmaf(a[i], b[j], acc[i][j]);
        }
        __syncthreads();
    }
    const float4 bi = *(const float4*)(bias + col0 + (tx << 2));
    #pragma unroll
    for (int i = 0; i < 8; ++i) {
        const int row = row0 + (ty << 3) + i;
        if (row < M) {
            float4 c;
            c.x = acc[i][0] + bi.x;
            c.y = acc[i][1] + bi.y;
            c.z = acc[i][2] + bi.z;
            c.w = acc[i][3] + bi.w;
            if (POST == 1) {
                c.x = fmaxf(c.x, 0.f); c.y = fmaxf(c.y, 0.f);
                c.z = fmaxf(c.z, 0.f); c.w = fmaxf(c.w, 0.f);
            }
            *(float4*)(C + (size_t)row * N + col0 + (tx << 2)) = c;
        }
    }
}

// ---------------------------------------------------------------------------
// FROZEN: scores 64x64 (round 3), same FP contraction as round 1.
// ---------------------------------------------------------------------------
__global__ __launch_bounds__(256)
void scores64_kernel(const float* __restrict__ Q, const float* __restrict__ Kx,
                     float* __restrict__ Sc)
{
    const int bh = blockIdx.z, b = bh >> 3, h = bh & 7;
    const int l0 = blockIdx.x << 6, s0 = blockIdx.y << 6;
    __shared__ float qs[64][68];
    __shared__ float ks[64][68];
    const int t = threadIdx.x;
    {
        const int r = t >> 4;
        const int c = (t & 15) << 2;
        #pragma unroll
        for (int i = 0; i < 4; ++i) {
            const int rr = r + (i << 4);
            const int l = l0 + rr, s = s0 + rr;
            float4 qv = make_float4(0.f, 0.f, 0.f, 0.f);
            float4 kv = make_float4(0.f, 0.f, 0.f, 0.f);
            if (l < LSEQ) qv = *(const float4*)(Q + ((size_t)(b * LSEQ + l)) * DD + h * EE + c);
            if (s < LSEQ) kv = *(const float4*)(Kx + ((size_t)(b * LSEQ + s)) * DD + h * EE + c);
            *(float4*)&qs[rr][c] = qv;
            *(float4*)&ks[rr][c] = kv;
        }
    }
    __syncthreads();
    const int tx = t & 15, ty = t >> 4;
    float acc[4][4] = {};
    for (int e = 0; e < EE; e += 4) {
        float4 q4[4], k4[4];
        #pragma unroll
        for (int i = 0; i < 4; ++i) q4[i] = *(const float4*)&qs[ty + (i << 4)][e];
        #pragma unroll
        for (int j = 0; j < 4; ++j) k4[j] = *(const float4*)&ks[tx + (j << 4)][e];
        #pragma unroll
        for (int i = 0; i < 4; ++i)
            #pragma unroll
            for (int j = 0; j < 4; ++j)
                acc[i][j] += q4[i].x * k4[j].x + q4[i].y * k4[j].y + q4[i].z * k4[j].z + q4[i].w * k4[j].w;
    }
    #pragma unroll
    for (int i = 0; i < 4; ++i) {
        const int l = l0 + ty + (i << 4);
        if (l < LSEQ) {
            #pragma unroll
            for (int j = 0; j < 4; ++j) {
                const int s = s0 + tx + (j << 4);
                if (s < LSEQ)
                    Sc[((size_t)bh * LSEQ + l) * LSEQ + s] = acc[i][j];
            }
        }
    }
}

// ---------------------------------------------------------------------------
// FROZEN: topk/softmax (bit-identical to round 1)
// ---------------------------------------------------------------------------
__global__ __launch_bounds__(256)
void topk_softmax_kernel(float* __restrict__ S)
{
    const int wave = threadIdx.x >> 6;
    const int lane = threadIdx.x & 63;
    const size_t row = (size_t)blockIdx.x * 4 + wave;
    float* p = S + row * LSEQ;
    float v[6], w[6];
    #pragma unroll
    for (int j = 0; j < 6; ++j) {
        const int idx = lane + (j << 6);
        v[j] = (idx < LSEQ) ? p[idx] : -INFINITY;
        w[j] = v[j];
    }
    float gmax = 0.f, kth = 0.f;
    #pragma unroll
    for (int it = 0; it < 10; ++it) {
        float m = w[0];
        #pragma unroll
        for (int j = 1; j < 6; ++j) m = fmaxf(m, w[j]);
        #pragma unroll
        for (int off = 32; off > 0; off >>= 1)
            m = fmaxf(m, __shfl_xor(m, off, 64));
        if (it == 0) gmax = m;
        kth = m;
        if (it < 9) {
            int which = -1;
            #pragma unroll
            for (int j = 0; j < 6; ++j)
                if (which < 0 && w[j] == m) which = j;
            const unsigned long long msk = __ballot(which >= 0);
            const int first = __ffsll(msk) - 1;
            if (lane == first) {
                #pragma unroll
                for (int j = 0; j < 6; ++j)
                    if (j == which) w[j] = -INFINITY;
            }
        }
    }
    float ssum = 0.f;
    float e[6];
    #pragma unroll
    for (int j = 0; j < 6; ++j) {
        e[j] = (v[j] >= kth) ? __expf(0.125f * (v[j] - gmax)) : 0.f;
        ssum += e[j];
    }
    #pragma unroll
    for (int off = 32; off > 0; off >>= 1) ssum += __shfl_xor(ssum, off, 64);
    const float inv = 1.f / ssum;
    #pragma unroll
    for (int j = 0; j < 6; ++j) {
        const int idx = lane + (j << 6);
        if (idx < LSEQ) p[idx] = e[j] * inv;
    }
}

// ---------------------------------------------------------------------------
// A@V: A fp32 (softmax weights), V bf16; ctx out bf16. FROZEN (round 3).
// ---------------------------------------------------------------------------
__global__ __launch_bounds__(256)
void av_bf16_kernel(const float* __restrict__ A, const unsigned short* __restrict__ V,
                    unsigned short* __restrict__ Out)
{
    const int bh = blockIdx.y, b = bh >> 3, h = bh & 7;
    const int l0 = blockIdx.x << 5;
    __shared__ float As[32][36];
    __shared__ float Vs[32][68];
    const int t = threadIdx.x;
    const int tx = t & 15, ty = t >> 4;
    float acc[2][4] = {};
    for (int s0 = 0; s0 < LSEQ; s0 += 32) {
        {
            const int r = t >> 3, c = (t & 7) << 2;
            const int l = l0 + r;
            const float* ap = A + ((size_t)bh * LSEQ + (l < LSEQ ? l : 0)) * LSEQ + s0 + c;
            #pragma unroll
            for (int jj = 0; jj < 4; ++jj) {
                const int s = s0 + c + jj;
                As[r][c + jj] = (l < LSEQ && s < LSEQ) ? ap[jj] : 0.f;
            }
        }
        #pragma unroll
        for (int pass = 0; pass < 2; ++pass) {
            const int r = (t >> 4) + (pass << 4), c = (t & 15) << 2;
            const int s = s0 + r;
            float4 vv = make_float4(0.f, 0.f, 0.f, 0.f);
            if (s < LSEQ) {
                const ushort4 u = *(const ushort4*)(V + ((size_t)(b * LSEQ + s)) * DD + h * EE + c);
                vv.x = bf2f(u.x); vv.y = bf2f(u.y); vv.z = bf2f(u.z); vv.w = bf2f(u.w);
            }
            *(float4*)&Vs[r][c] = vv;
        }
        __syncthreads();
        #pragma unroll
        for (int ss = 0; ss < 32; ++ss) {
            const float a0 = As[(ty << 1) + 0][ss];
            const float a1 = As[(ty << 1) + 1][ss];
            const float4 vv = *(const float4*)&Vs[ss][tx << 2];
            acc[0][0] = fmaf(a0, vv.x, acc[0][0]);
            acc[0][1] = fmaf(a0, vv.y, acc[0][1]);
            acc[0][2] = fmaf(a0, vv.z, acc[0][2]);
            acc[0][3] = fmaf(a0, vv.w, acc[0][3]);
            acc[1][0] = fmaf(a1, vv.x, acc[1][0]);
            acc[1][1] = fmaf(a1, vv.y, acc[1][1]);
            acc[1][2] = fmaf(a1, vv.z, acc[1][2]);
            acc[1][3] = fmaf(a1, vv.w, acc[1][3]);
        }
        __syncthreads();
    }
    #pragma unroll
    for (int i = 0; i < 2; ++i) {
        const int l = l0 + (ty << 1) + i;
        if (l < LSEQ) {
            ushort4 o;
            o.x = f2bf(acc[i][0]); o.y = f2bf(acc[i][1]);
            o.z = f2bf(acc[i][2]); o.w = f2bf(acc[i][3]);
            *(ushort4*)(Out + ((size_t)(b * LSEQ + l)) * DD + h * EE + (tx << 2)) = o;
        }
    }
}

// ---------------------------------------------------------------------------
// fp32 -> bf16 convert (x staging for MFMA); pads tail rows with zeros.
// ---------------------------------------------------------------------------
__global__ __launch_bounds__(256)
void f32_to_bf16_kernel(const float* __restrict__ X, unsigned short* __restrict__ Y,
                        long long nvalid, long long ntotal)
{
    const long long i = ((long long)blockIdx.x * 256 + threadIdx.x) * 4;
    if (i >= ntotal) return;
    float4 v = make_float4(0.f, 0.f, 0.f, 0.f);
    if (i < nvalid) v = *(const float4*)(X + i);
    ushort4 o;
    o.x = f2bf(v.x); o.y = f2bf(v.y); o.z = f2bf(v.z); o.w = f2bf(v.w);
    *(ushort4*)(Y + i) = o;
}

// ---------------------------------------------------------------------------
// Weight prep: fp32 W[K][N] -> bf16 W^T[N][K]
// ---------------------------------------------------------------------------
__global__ __launch_bounds__(256)
void transpose_w_kernel(const float* __restrict__ W, unsigned short* __restrict__ Wt,
                        int K, int N)
{
    __shared__ unsigned short s[32][33];
    const int n0 = blockIdx.x << 5, k0 = blockIdx.y << 5;
    const int tx = threadIdx.x & 31, ty = threadIdx.x >> 5;
    #pragma unroll
    for (int i = 0; i < 32; i += 8)
        s[ty + i][tx] = f2bf(W[(size_t)(k0 + ty + i) * N + n0 + tx]);
    __syncthreads();
    #pragma unroll
    for (int i = 0; i < 32; i += 8)
        Wt[(size_t)(n0 + ty + i) * K + k0 + tx] = s[tx][ty + i];
}

// ---------------------------------------------------------------------------
// bf16 MFMA GEMM core macro pieces (m97 structure + XOR LDS swizzle + XCD
// remap). Single-output version.
// ---------------------------------------------------------------------------
template<int RES, int POST, int OUTBF>
__global__ __launch_bounds__(256)
void mgemm_kernel(const unsigned short* __restrict__ A, const unsigned short* __restrict__ Bt,
                  const float* __restrict__ bias, const void* __restrict__ Rres,
                  void* __restrict__ Cout, int M, int K, int N)
{
    __shared__ unsigned short As[128 * 32];
    __shared__ unsigned short Bs[128 * 32];
    const int t = threadIdx.x;
    const int lane = t & 63;
    const int wave = t >> 6;
    int row0, col0;
    xcd_remap(blockIdx.y * gridDim.x + blockIdx.x, gridDim.x * gridDim.y, gridDim.x, row0, col0);
    const int wm = (wave >> 1) << 6, wn = (wave & 1) << 6;
    const int r0 = t >> 2;
    const int kh = ((t & 3) ^ ((t >> 3) & 3)) << 3;
    const unsigned short* Ag0 = A + (size_t)(row0 + r0) * K + kh;
    const unsigned short* Ag1 = Ag0 + (size_t)64 * K;
    const unsigned short* Bg0 = Bt + (size_t)(col0 + r0) * K + kh;
    const unsigned short* Bg1 = Bg0 + (size_t)64 * K;
    unsigned short* As0 = As + t * 8;  unsigned short* As1 = As0 + 2048;
    unsigned short* Bs0 = Bs + t * 8;  unsigned short* Bs1 = Bs0 + 2048;
    const int fm = lane & 15, q = lane >> 4;
    int aoff[4], boff[4];
    #pragma unroll
    for (int i = 0; i < 4; ++i) {
        const int Ra = wm + (i << 4) + fm;
        aoff[i] = Ra * 32 + ((q ^ ((Ra >> 1) & 3)) << 3);
        const int Rb = wn + (i << 4) + fm;
        boff[i] = Rb * 32 + ((q ^ ((Rb >> 1) & 3)) << 3);
    }
    f32x4 acc[4][4] = {};
    for (int k0 = 0; k0 < K; k0 += 32) {
        GLDS16(Ag0 + k0, As0);
        GLDS16(Ag1 + k0, As1);
        GLDS16(Bg0 + k0, Bs0);
        GLDS16(Bg1 + k0, Bs1);
        __syncthreads();
        bf16x8 af[4], bfr[4];
        #pragma unroll
        for (int i = 0; i < 4; ++i) {
            af[i]  = *(const bf16x8*)(As + aoff[i]);
            bfr[i] = *(const bf16x8*)(Bs + boff[i]);
        }
        #pragma unroll
        for (int i = 0; i < 4; ++i)
            #pragma unroll
            for (int j = 0; j < 4; ++j)
                acc[i][j] = __builtin_amdgcn_mfma_f32_16x16x32_bf16(af[i], bfr[j], acc[i][j], 0, 0, 0);
        __syncthreads();
    }
    const int qr = (lane >> 4) << 2;
    #pragma unroll
    for (int j = 0; j < 4; ++j) {
        const int gcol = col0 + wn + (j << 4) + fm;
        const float bj = bias[gcol];
        #pragma unroll
        for (int i = 0; i < 4; ++i) {
            const int rb = row0 + wm + (i << 4) + qr;
            #pragma unroll
            for (int rg = 0; rg < 4; ++rg) {
                const int grow = rb + rg;
                if (grow < M) {
                    float c = acc[i][j][rg] + bj;
                    if (RES == 1) c += ((const float*)Rres)[(size_t)grow * N + gcol];
                    if (RES == 2) c += bf2f(((const unsigned short*)Rres)[(size_t)grow * N + gcol]);
                    if (POST == 1) c = fmaxf(c, 0.f);
                    if (POST == 2) c = c >= 0.f ? c : 0.5f * c;
                    if (OUTBF) ((unsigned short*)Cout)[(size_t)grow * N + gcol] = f2bf(c);
                    else       ((float*)Cout)[(size_t)grow * N + gcol] = c;
                }
            }
        }
    }
}

// ---------------------------------------------------------------------------
// 3-segment fused bf16 MFMA GEMM: one pass over A computes three GEMMs whose
// weights are concatenated as Bt[N0+N1+N2][K]. Segment widths are multiples
// of 128 so each block maps to exactly one segment (uniform branch).
// P*: 0 none, 1 relu. All outputs bf16.
// ---------------------------------------------------------------------------
template<int N0, int N1, int N2, int P0, int P1, int P2>
__global__ __launch_bounds__(256)
void mgemm3_kernel(const unsigned short* __restrict__ A, const unsigned short* __restrict__ Bt,
                   const float* __restrict__ b0, const float* __restrict__ b1,
                   const float* __restrict__ b2,
                   unsigned short* __restrict__ o0, unsigned short* __restrict__ o1,
                   unsigned short* __restrict__ o2, int M, int K)
{
    __shared__ unsigned short As[128 * 32];
    __shared__ unsigned short Bs[128 * 32];
    const int t = threadIdx.x;
    const int lane = t & 63;
    const int wave = t >> 6;
    int row0, col0;
    xcd_remap(blockIdx.y * gridDim.x + blockIdx.x, gridDim.x * gridDim.y, gridDim.x, row0, col0);
    const int wm = (wave >> 1) << 6, wn = (wave & 1) << 6;
    const int r0 = t >> 2;
    const int kh = ((t & 3) ^ ((t >> 3) & 3)) << 3;
    const unsigned short* Ag0 = A + (size_t)(row0 + r0) * K + kh;
    const unsigned short* Ag1 = Ag0 + (size_t)64 * K;
    const unsigned short* Bg0 = Bt + (size_t)(col0 + r0) * K + kh;
    const unsigned short* Bg1 = Bg0 + (size_t)64 * K;
    unsigned short* As0 = As + t * 8;  unsigned short* As1 = As0 + 2048;
    unsigned short* Bs0 = Bs + t * 8;  unsigned short* Bs1 = Bs0 + 2048;
    const int fm = lane & 15, q = lane >> 4;
    int aoff[4], boff[4];
    #pragma unroll
    for (int i = 0; i < 4; ++i) {
        const int Ra = wm + (i << 4) + fm;
        aoff[i] = Ra * 32 + ((q ^ ((Ra >> 1) & 3)) << 3);
        const int Rb = wn + (i << 4) + fm;
        boff[i] = Rb * 32 + ((q ^ ((Rb >> 1) & 3)) << 3);
    }
    f32x4 acc[4][4] = {};
    for (int k0 = 0; k0 < K; k0 += 32) {
        GLDS16(Ag0 + k0, As0);
        GLDS16(Ag1 + k0, As1);
        GLDS16(Bg0 + k0, Bs0);
        GLDS16(Bg1 + k0, Bs1);
        __syncthreads();
        bf16x8 af[4], bfr[4];
        #pragma unroll
        for (int i = 0; i < 4; ++i) {
            af[i]  = *(const bf16x8*)(As + aoff[i]);
            bfr[i] = *(const bf16x8*)(Bs + boff[i]);
        }
        #pragma unroll
        for (int i = 0; i < 4; ++i)
            #pragma unroll
            for (int j = 0; j < 4; ++j)
                acc[i][j] = __builtin_amdgcn_mfma_f32_16x16x32_bf16(af[i], bfr[j], acc[i][j], 0, 0, 0);
        __syncthreads();
    }
    // block-uniform segment select
    unsigned short* outp; const float* bp; int segN, segbase, post;
    if (col0 < N0)           { outp = o0; bp = b0; segN = N0; segbase = 0;       post = P0; }
    else if (col0 < N0 + N1) { outp = o1; bp = b1; segN = N1; segbase = N0;      post = P1; }
    else                     { outp = o2; bp = b2; segN = N2; segbase = N0 + N1; post = P2; }
    const int qr = (lane >> 4) << 2;
    #pragma unroll
    for (int j = 0; j < 4; ++j) {
        const int gcol = col0 + wn + (j << 4) + fm;
        const int scol = gcol - segbase;
        const float bj = bp[scol];
        #pragma unroll
        for (int i = 0; i < 4; ++i) {
            const int rb = row0 + wm + (i << 4) + qr;
            #pragma unroll
            for (int rg = 0; rg < 4; ++rg) {
                const int grow = rb + rg;
                if (grow < M) {
                    float c = acc[i][j][rg] + bj;
                    if (post == 1) c = fmaxf(c, 0.f);
                    outp[(size_t)grow * segN + scol] = f2bf(c);
                }
            }
        }
    }
}

// ---------------------------------------------------------------------------
// Point-wise attention, bf16 in/out, fp32 math, online softmax.
// ---------------------------------------------------------------------------
template<int NQ, int NS>
__global__ __launch_bounds__(256)
void pw_attn_bf16(const unsigned short* __restrict__ Q, const unsigned short* __restrict__ Kx,
                  const unsigned short* __restrict__ V, unsigned short* __restrict__ Out)
{
    const long long gid = (long long)blockIdx.x * 256 + threadIdx.x;
    const long long n = gid / NQ;
    const int l = (int)(gid % NQ);
    float qf[16];
    {
        const uint4* qp = (const uint4*)(Q + (size_t)n * NQ * 16 + (size_t)l * 16);
        bf8_to_f(qp[0], qf); bf8_to_f(qp[1], qf + 8);
    }
    const unsigned short* kp = Kx + (size_t)n * NS * 16;
    const unsigned short* vp = V  + (size_t)n * NS * 16;
    float m = -INFINITY, denom = 0.f;
    float acc[16] = {};
    for (int s = 0; s < NS; ++s) {
        float kf[16], vf[16];
        const uint4* kr = (const uint4*)(kp + s * 16);
        bf8_to_f(kr[0], kf); bf8_to_f(kr[1], kf + 8);
        float sc = 0.f;
        #pragma unroll
        for (int j = 0; j < 16; ++j) sc = fmaf(qf[j], kf[j], sc);
        sc *= 0.25f;
        const float nm = fmaxf(m, sc);
        const float fold = __expf(m - nm);
        const float es = __expf(sc - nm);
        denom = denom * fold + es;
        const uint4* vr = (const uint4*)(vp + s * 16);
        bf8_to_f(vr[0], vf); bf8_to_f(vr[1], vf + 8);
        #pragma unroll
        for (int j = 0; j < 16; ++j) acc[j] = acc[j] * fold + es * vf[j];
        m = nm;
    }
    const float inv = 1.f / denom;
    uint4 o0, o1;
    o0.x = packbf(acc[0] * inv,  acc[1] * inv);
    o0.y = packbf(acc[2] * inv,  acc[3] * inv);
    o0.z = packbf(acc[4] * inv,  acc[5] * inv);
    o0.w = packbf(acc[6] * inv,  acc[7] * inv);
    o1.x = packbf(acc[8] * inv,  acc[9] * inv);
    o1.y = packbf(acc[10] * inv, acc[11] * inv);
    o1.z = packbf(acc[12] * inv, acc[13] * inv);
    o1.w = packbf(acc[14] * inv, acc[15] * inv);
    uint4* op = (uint4*)(Out + (size_t)n * NQ * 16 + (size_t)l * 16);
    op[0] = o0; op[1] = o1;
}

// ---------------------------------------------------------------------------
// t = LayerNorm(elu(u)) * g + b ; bf16 in / bf16 out, fp32 math.
// ---------------------------------------------------------------------------
__global__ __launch_bounds__(256)
void elu_ln_bf16_kernel(const unsigned short* __restrict__ U, const float* __restrict__ g,
                        const float* __restrict__ bb, unsigned short* __restrict__ Out)
{
    const int row = blockIdx.x;
    const int t = threadIdx.x;
    const size_t base = (size_t)row * DFF + (size_t)t * 8;
    float vals[8];
    {
        const uint4 u4 = *(const uint4*)(U + base);
        bf8_to_f(u4, vals);
    }
    float s = 0.f, sq = 0.f;
    #pragma unroll
    for (int j = 0; j < 8; ++j) {
        const float e = vals[j] > 0.f ? vals[j] : expm1f(vals[j]);
        vals[j] = e;
        s += e; sq += e * e;
    }
    #pragma unroll
    for (int off = 32; off > 0; off >>= 1) {
        s  += __shfl_xor(s,  off, 64);
        sq += __shfl_xor(sq, off, 64);
    }
    __shared__ float rs[4], rq[4];
    const int wave = t >> 6, lane = t & 63;
    if (lane == 0) { rs[wave] = s; rq[wave] = sq; }
    __syncthreads();
    const float ts = rs[0] + rs[1] + rs[2] + rs[3];
    const float tq = rq[0] + rq[1] + rq[2] + rq[3];
    const float mean = ts * (1.f / 2048.f);
    const float var  = tq * (1.f / 2048.f) - mean * mean;
    const float rinv = rsqrtf(var + 1e-5f);
    const float4 g0 = *(const float4*)(g + t * 8);
    const float4 g1 = *(const float4*)(g + t * 8 + 4);
    const float4 b0 = *(const float4*)(bb + t * 8);
    const float4 b1 = *(const float4*)(bb + t * 8 + 4);
    float o[8];
    o[0] = (vals[0] - mean) * rinv * g0.x + b0.x;
    o[1] = (vals[1] - mean) * rinv * g0.y + b0.y;
    o[2] = (vals[2] - mean) * rinv * g0.z + b0.z;
    o[3] = (vals[3] - mean) * rinv * g0.w + b0.w;
    o[4] = (vals[4] - mean) * rinv * g1.x + b1.x;
    o[5] = (vals[5] - mean) * rinv * g1.y + b1.y;
    o[6] = (vals[6] - mean) * rinv * g1.z + b1.z;
    o[7] = (vals[7] - mean) * rinv * g1.w + b1.w;
    uint4 ov;
    ov.x = packbf(o[0], o[1]); ov.y = packbf(o[2], o[3]);
    ov.z = packbf(o[4], o[5]); ov.w = packbf(o[6], o[7]);
    *(uint4*)(Out + base) = ov;
}

// ---------------------------------------------------------------------------
extern "C" void kernel_launch(void* const* d_in, const int* in_sizes, int n_in,
                              void* d_out, int out_size, void* d_ws, size_t ws_size,
                              hipStream_t stream)
{
    const float* x        = (const float*)d_in[0];
    const float* attn_q_w = (const float*)d_in[1];
    const float* attn_q_b = (const float*)d_in[2];
    const float* attn_k_w = (const float*)d_in[3];
    const float* attn_k_b = (const float*)d_in[4];
    const float* attn_v_w = (const float*)d_in[5];
    const float* attn_v_b = (const float*)d_in[6];
    const float* attn_o_w = (const float*)d_in[7];
    const float* attn_o_b = (const float*)d_in[8];
    const float* enc_w    = (const float*)d_in[9];
    const float* enc_b    = (const float*)d_in[10];
    const float* ff1_q_w  = (const float*)d_in[11];
    const float* ff1_q_b  = (const float*)d_in[12];
    const float* ff1_k_w  = (const float*)d_in[13];
    const float* ff1_k_b  = (const float*)d_in[14];
    const float* ff1_v_w  = (const float*)d_in[15];
    const float* ff1_v_b  = (const float*)d_in[16];
    const float* ff1_o_w  = (const float*)d_in[17];
    const float* ff1_o_b  = (const float*)d_in[18];
    const float* ff2_q_w  = (const float*)d_in[19];
    const float* ff2_q_b  = (const float*)d_in[20];
    const float* ff2_k_w  = (const float*)d_in[21];
    const float* ff2_k_b  = (const float*)d_in[22];
    const float* ff2_v_w  = (const float*)d_in[23];
    const float* ff2_v_b  = (const float*)d_in[24];
    const float* ff2_o_w  = (const float*)d_in[25];
    const float* ff2_o_b  = (const float*)d_in[26];
    const float* ln_g     = (const float*)d_in[27];
    const float* ln_b     = (const float*)d_in[28];
    (void)in_sizes; (void)n_in; (void)out_size; (void)ws_size;

    float* yout = (float*)d_out;                      // [20544, 512] fp32
    float* Aout = yout + (size_t)N_ROWS * DD;         // [B,H,L,L] fp32

    // ---- workspace carve ----
    char* cur = (char*)d_ws;
    auto alloc = [&](size_t bytes) -> void* {
        void* p = (void*)cur;
        cur += (bytes + 255) & ~(size_t)255;
        return p;
    };
    const size_t F32S = (size_t)N_ROWS * DD * 4;      // fp32 [N,512]
    const size_t BFS  = (size_t)MP * DD * 2;          // bf16 [MP,512]
    const size_t BFG  = (size_t)MP * DFF * 2;         // bf16 [MP,2048]
    float* A1 = (float*)alloc(F32S);                  // q (frozen fp32)
    float* A2 = (float*)alloc(F32S);                  // k
    unsigned short* xbf = (unsigned short*)alloc(BFS);// x in bf16 [MP,512]
    unsigned short* S1 = (unsigned short*)alloc(BFS); // ctx -> z -> q2
    unsigned short* S2 = (unsigned short*)alloc(BFS); // ly -> k1 -> V2
    unsigned short* S3 = (unsigned short*)alloc(BFS); // v (bf16) -> v1
    unsigned short* G1 = (unsigned short*)alloc(BFG); // q1 -> t
    unsigned short* G2 = (unsigned short*)alloc(BFG); // V1 -> k2
    unsigned short* G3 = (unsigned short*)alloc(BFG); // u  -> v2
    unsigned short* wt_av   = (unsigned short*)alloc((size_t)DD * DD * 2);
    unsigned short* wt_ao   = (unsigned short*)alloc((size_t)DD * DD * 2);
    unsigned short* wt_enc  = (unsigned short*)alloc((size_t)DD * DD * 2);
    unsigned short* wt_f1o  = (unsigned short*)alloc((size_t)DFF * DFF * 2);
    unsigned short* wt_f2o  = (unsigned short*)alloc((size_t)DD * DD * 2);
    unsigned short* wt_f1qkv= (unsigned short*)alloc((size_t)(DFF + DD + DD) * DD * 2);   // [3072][512]
    unsigned short* wt_f2qkv= (unsigned short*)alloc((size_t)(DD + DFF + DFF) * DFF * 2); // [4608][2048]

    const dim3 blk(256);
    const dim3 gq(161, DD / 64);                      // sgemm128: 161 x 8
    const dim3 gm512(DD / 128, MP / 128);             // 4 x 161
    const dim3 gm2048(DFF / 128, MP / 128);           // 16 x 161
    const dim3 gf1(24, MP / 128);                     // 3072/128 x 161
    const dim3 gf2(36, MP / 128);                     // 4608/128 x 161

    // ---- weight prep ----
    transpose_w_kernel<<<dim3(DD/32,  DD/32),  blk, 0, stream>>>(attn_v_w, wt_av,  DD,  DD);
    transpose_w_kernel<<<dim3(DD/32,  DD/32),  blk, 0, stream>>>(attn_o_w, wt_ao,  DD,  DD);
    transpose_w_kernel<<<dim3(DD/32,  DD/32),  blk, 0, stream>>>(enc_w,    wt_enc, DD,  DD);
    transpose_w_kernel<<<dim3(DFF/32, DFF/32), blk, 0, stream>>>(ff1_o_w,  wt_f1o, DFF, DFF);
    transpose_w_kernel<<<dim3(DD/32,  DD/32),  blk, 0, stream>>>(ff2_o_w,  wt_f2o, DD,  DD);
    // ff1 fused weights: rows [0,2048)=q1, [2048,2560)=k1, [2560,3072)=v1 ; K=512
    transpose_w_kernel<<<dim3(DFF/32, DD/32),  blk, 0, stream>>>(ff1_q_w, wt_f1qkv,                       DD, DFF);
    transpose_w_kernel<<<dim3(DD/32,  DD/32),  blk, 0, stream>>>(ff1_k_w, wt_f1qkv + (size_t)DFF * DD,    DD, DD);
    transpose_w_kernel<<<dim3(DD/32,  DD/32),  blk, 0, stream>>>(ff1_v_w, wt_f1qkv + (size_t)(DFF+DD)*DD, DD, DD);
    // ff2 fused weights: rows [0,512)=q2, [512,2560)=k2, [2560,4608)=v2 ; K=2048
    transpose_w_kernel<<<dim3(DD/32,  DFF/32), blk, 0, stream>>>(ff2_q_w, wt_f2qkv,                        DFF, DD);
    transpose_w_kernel<<<dim3(DFF/32, DFF/32), blk, 0, stream>>>(ff2_k_w, wt_f2qkv + (size_t)DD * DFF,     DFF, DFF);
    transpose_w_kernel<<<dim3(DFF/32, DFF/32), blk, 0, stream>>>(ff2_v_w, wt_f2qkv + (size_t)(DD+DFF)*DFF, DFF, DFF);
    f32_to_bf16_kernel<<<dim3((MP * DD / 4 + 255) / 256), blk, 0, stream>>>(
        x, xbf, (long long)N_ROWS * DD, (long long)MP * DD);

    // ---- gattn: q,k frozen fp32; v via bf16 MFMA ----
    sgemm128_kernel<1><<<gq, blk, 0, stream>>>(x, attn_q_w, attn_q_b, A1, N_ROWS, DD, DD);   // q=relu
    sgemm128_kernel<0><<<gq, blk, 0, stream>>>(x, attn_k_w, attn_k_b, A2, N_ROWS, DD, DD);   // k
    mgemm_kernel<0,1,1><<<gm512, blk, 0, stream>>>(xbf, wt_av, attn_v_b, nullptr, S3, N_ROWS, DD, DD); // v=relu bf16
    scores64_kernel<<<dim3(6, 6, BB * HH), blk, 0, stream>>>(A1, A2, Aout);
    topk_softmax_kernel<<<dim3((BB * HH * LSEQ) / 4), blk, 0, stream>>>(Aout);
    av_bf16_kernel<<<dim3(11, BB * HH), blk, 0, stream>>>(Aout, S3, S1);                     // ctx bf16

    // ---- y path, all bf16 MFMA ----
    mgemm_kernel<1,2,1><<<gm512, blk, 0, stream>>>(S1, wt_ao, attn_o_b, x, S2, N_ROWS, DD, DD);     // ly = leaky(x+ctx@Wo+b)
    mgemm_kernel<0,0,1><<<gm512, blk, 0, stream>>>(S2, wt_enc, enc_b, nullptr, S1, N_ROWS, DD, DD); // z
    mgemm3_kernel<DFF,DD,DD, 1,0,1><<<gf1, blk, 0, stream>>>(S1, wt_f1qkv,
        ff1_q_b, ff1_k_b, ff1_v_b, G1, S2, S3, N_ROWS, DD);                                 // q1,k1,v1 (one A pass)
    pw_attn_bf16<128,32><<<dim3((N_ROWS * 128) / 256), blk, 0, stream>>>(G1, S2, S3, G2);   // V1
    mgemm_kernel<2,0,1><<<gm2048, blk, 0, stream>>>(G2, wt_f1o, ff1_o_b, G1, G3, N_ROWS, DFF, DFF); // u = q1 + V1@Wo+b
    elu_ln_bf16_kernel<<<dim3(N_ROWS), blk, 0, stream>>>(G3, ln_g, ln_b, G1);               // t
    mgemm3_kernel<DD,DFF,DFF, 1,0,1><<<gf2, blk, 0, stream>>>(G1, wt_f2qkv,
        ff2_q_b, ff2_k_b, ff2_v_b, S1, G2, G3, N_ROWS, DFF);                                // q2,k2,v2 (one A pass)
    pw_attn_bf16<32,128><<<dim3((N_ROWS * 32) / 256), blk, 0, stream>>>(S1, G2, G3, S2);    // V2
    mgemm_kernel<2,0,0><<<gm512, blk, 0, stream>>>(S2, wt_f2o, ff2_o_b, S1, yout, N_ROWS, DD, DD);  // yout fp32
}